// Round 1
// baseline (3178.650 us; speedup 1.0000x reference)
//
#include <hip/hip_runtime.h>
#include <cstddef>
#include <cstdint>

#define NBATCH 8
#define NPTS   2048
#define KNN    20

// ---------------------------------------------------------------------------
// transpose (B,3,N) -> (B,N,3)
// ---------------------------------------------------------------------------
__global__ void k_transpose(const float* __restrict__ x, float* __restrict__ h0) {
  int i = blockIdx.x * 256 + threadIdx.x;
  if (i >= NBATCH * NPTS * 3) return;
  int c = i % 3;
  int n = (i / 3) % NPTS;
  int b = i / (3 * NPTS);
  h0[i] = x[((size_t)b * 3 + c) * NPTS + n];
}

// ---------------------------------------------------------------------------
// pairwise "distance" pd = 2*dot(x_n,x_m) - |x_n|^2 - |x_m|^2 for ONE batch.
// grid (N/64, N/64), block 256, 4x4 microtile per thread.
// ---------------------------------------------------------------------------
template <int C>
__global__ __launch_bounds__(256) void k_dist(const float* __restrict__ xb,
                                              float* __restrict__ dist) {
  constexpr int PAD = (C % 4 == 0) ? 4 : 1;   // keep 16B alignment when vectorized
  constexpr int S = C + PAD;
  __shared__ __attribute__((aligned(16))) float rows[64 * S];
  __shared__ __attribute__((aligned(16))) float cols[64 * S];
  __shared__ float sq[128];

  const int rt = blockIdx.y, ct = blockIdx.x;
  const int tid = threadIdx.x;

  for (int e = tid; e < 64 * C; e += 256) {
    int i = e / C, c = e - i * C;
    rows[i * S + c] = xb[(size_t)(rt * 64 + i) * C + c];
    cols[i * S + c] = xb[(size_t)(ct * 64 + i) * C + c];
  }
  __syncthreads();
  if (tid < 128) {
    const float* p = (tid < 64) ? (rows + tid * S) : (cols + (tid - 64) * S);
    float s = 0.f;
    for (int c = 0; c < C; c++) s += p[c] * p[c];
    sq[tid] = s;
  }
  __syncthreads();

  const int r0 = (tid >> 4) * 4;
  const int c0 = (tid & 15) * 4;
  float acc[4][4] = {};

  if constexpr (C % 4 == 0) {
    for (int c = 0; c < C; c += 4) {
      float4 ra[4], cb[4];
#pragma unroll
      for (int i = 0; i < 4; i++) ra[i] = *(const float4*)&rows[(r0 + i) * S + c];
#pragma unroll
      for (int j = 0; j < 4; j++) cb[j] = *(const float4*)&cols[(c0 + j) * S + c];
#pragma unroll
      for (int i = 0; i < 4; i++)
#pragma unroll
        for (int j = 0; j < 4; j++)
          acc[i][j] += ra[i].x * cb[j].x + ra[i].y * cb[j].y +
                       ra[i].z * cb[j].z + ra[i].w * cb[j].w;
    }
  } else {
    for (int c = 0; c < C; c++) {
      float ra[4], cb[4];
#pragma unroll
      for (int i = 0; i < 4; i++) ra[i] = rows[(r0 + i) * S + c];
#pragma unroll
      for (int j = 0; j < 4; j++) cb[j] = cols[(c0 + j) * S + c];
#pragma unroll
      for (int i = 0; i < 4; i++)
#pragma unroll
        for (int j = 0; j < 4; j++) acc[i][j] += ra[i] * cb[j];
    }
  }

#pragma unroll
  for (int i = 0; i < 4; i++) {
    float sr = sq[r0 + i];
    float4 v;
    v.x = 2.f * acc[i][0] - sr - sq[64 + c0 + 0];
    v.y = 2.f * acc[i][1] - sr - sq[64 + c0 + 1];
    v.z = 2.f * acc[i][2] - sr - sq[64 + c0 + 2];
    v.w = 2.f * acc[i][3] - sr - sq[64 + c0 + 3];
    *(float4*)&dist[(size_t)(rt * 64 + r0 + i) * NPTS + ct * 64 + c0] = v;
  }
}

// ---------------------------------------------------------------------------
// top-20 per row (one batch). block per row. tie-break: lowest index (matches
// jax.lax.top_k stable descending sort).
// ---------------------------------------------------------------------------
__global__ __launch_bounds__(256) void k_topk(const float* __restrict__ dist,
                                              int* __restrict__ idx_out) {
  const int n = blockIdx.x;
  const float* drow = dist + (size_t)n * NPTS;
  __shared__ float sd[NPTS];
  __shared__ float rv[4];
  __shared__ int ri[4];
  const int tid = threadIdx.x;

  for (int i = tid; i < NPTS; i += 256) sd[i] = drow[i];
  __syncthreads();

  for (int k = 0; k < KNN; k++) {
    float bv = -3.0e38f;
    int bi = NPTS;
    for (int i = tid; i < NPTS; i += 256) {
      float v = sd[i];
      if (v > bv) { bv = v; bi = i; }  // increasing i: keeps lowest index on tie
    }
#pragma unroll
    for (int off = 32; off > 0; off >>= 1) {
      float ov = __shfl_down(bv, off);
      int oi = __shfl_down(bi, off);
      if (ov > bv || (ov == bv && oi < bi)) { bv = ov; bi = oi; }
    }
    if ((tid & 63) == 0) { rv[tid >> 6] = bv; ri[tid >> 6] = bi; }
    __syncthreads();
    if (tid == 0) {
#pragma unroll
      for (int w = 1; w < 4; w++)
        if (rv[w] > bv || (rv[w] == bv && ri[w] < bi)) { bv = rv[w]; bi = ri[w]; }
      idx_out[n * KNN + k] = bi;
      sd[bi] = -3.0e38f;
    }
    __syncthreads();
  }
}

// ---------------------------------------------------------------------------
// edge conv: out[b,n,o] = max_k leaky((feat@w)*g + b), feat=[nb-ctr, ctr].
// k-invariant part t0[o] = sum_c ctr[c]*w[C+c,o] hoisted out of k loop.
// ---------------------------------------------------------------------------
template <int C, int O>
__global__ __launch_bounds__(256) void k_edge(const float* __restrict__ x,
                                              const int* __restrict__ knn,
                                              const float* __restrict__ w,
                                              const float* __restrict__ g,
                                              const float* __restrict__ bta,
                                              float* __restrict__ out) {
  constexpr int NPB = 256 / O;  // points per block
  __shared__ __attribute__((aligned(16))) float nbd[NPB * KNN * C];
  __shared__ float ctr[NPB * C];

  const int blk = blockIdx.x;
  const int b = blk / (NPTS / NPB);
  const int n0 = (blk % (NPTS / NPB)) * NPB;
  const int tid = threadIdx.x;
  const float* xb = x + (size_t)b * NPTS * C;

  for (int e = tid; e < NPB * C; e += 256) {
    int p = e / C, c = e - p * C;
    ctr[e] = xb[(size_t)(n0 + p) * C + c];
  }
  __syncthreads();
  for (int e = tid; e < NPB * KNN * C; e += 256) {
    int c = e % C;
    int t = e / C;
    int k = t % KNN;
    int p = t / KNN;
    int m = knn[(size_t)(b * NPTS + n0 + p) * KNN + k];
    nbd[e] = xb[(size_t)m * C + c] - ctr[p * C + c];
  }
  __syncthreads();

  const int p = tid / O;
  const int o = tid - p * O;

  float t0 = 0.f;
  for (int c = 0; c < C; c++) t0 += ctr[p * C + c] * w[(C + c) * O + o];

  float acc[KNN];
#pragma unroll
  for (int k = 0; k < KNN; k++) acc[k] = t0;

  const float* nb_p = nbd + p * KNN * C;
  if constexpr (C % 4 == 0) {
    for (int c = 0; c < C; c += 4) {
      float wv0 = w[(c + 0) * O + o];
      float wv1 = w[(c + 1) * O + o];
      float wv2 = w[(c + 2) * O + o];
      float wv3 = w[(c + 3) * O + o];
#pragma unroll
      for (int k = 0; k < KNN; k++) {
        float4 f = *(const float4*)&nb_p[k * C + c];
        acc[k] += f.x * wv0 + f.y * wv1 + f.z * wv2 + f.w * wv3;
      }
    }
  } else {
    for (int c = 0; c < C; c++) {
      float wv = w[c * O + o];
#pragma unroll
      for (int k = 0; k < KNN; k++) acc[k] += nb_p[k * C + c] * wv;
    }
  }

  const float gv = g[o], bv = bta[o];
  float mx = -3.0e38f;
#pragma unroll
  for (int k = 0; k < KNN; k++) {
    float h = acc[k] * gv + bv;
    h = (h >= 0.f) ? h : 0.2f * h;
    mx = fmaxf(mx, h);
  }
  out[(size_t)(b * NPTS + n0 + p) * O + o] = mx;
}

// ---------------------------------------------------------------------------
// point MLP 512->1024 + leaky + partial max/sum pool over a 16-point tile.
// block: 256 threads, thread owns 4 e-channels x 16 points (64 accs).
// ---------------------------------------------------------------------------
__global__ __launch_bounds__(256) void k_mlp5(const float* __restrict__ x1,
                                              const float* __restrict__ x2,
                                              const float* __restrict__ x3,
                                              const float* __restrict__ x4,
                                              const float* __restrict__ w5,
                                              const float* __restrict__ g5,
                                              const float* __restrict__ b5,
                                              float* __restrict__ pmax,
                                              float* __restrict__ psum) {
  constexpr int TN = 16;
  __shared__ __attribute__((aligned(16))) float feat[TN * 512];
  const int blk = blockIdx.x;
  const int b = blk / (NPTS / TN);
  const int n0 = (blk % (NPTS / TN)) * TN;
  const int tid = threadIdx.x;

  for (int e = tid; e < TN * 512; e += 256) {
    int nn = e >> 9, c = e & 511;
    size_t n = (size_t)b * NPTS + n0 + nn;
    float v;
    if (c < 64)        v = x1[n * 64 + c];
    else if (c < 128)  v = x2[n * 64 + (c - 64)];
    else if (c < 256)  v = x3[n * 128 + (c - 128)];
    else               v = x4[n * 256 + (c - 256)];
    feat[e] = v;
  }
  __syncthreads();

  float acc[TN][4];
#pragma unroll
  for (int nn = 0; nn < TN; nn++)
#pragma unroll
    for (int j = 0; j < 4; j++) acc[nn][j] = 0.f;

  for (int c = 0; c < 512; c += 4) {
    float wv[4][4];
#pragma unroll
    for (int cc = 0; cc < 4; cc++)
#pragma unroll
      for (int j = 0; j < 4; j++)
        wv[cc][j] = w5[(size_t)(c + cc) * 1024 + tid + j * 256];
#pragma unroll
    for (int nn = 0; nn < TN; nn++) {
      float4 f = *(const float4*)&feat[nn * 512 + c];
#pragma unroll
      for (int j = 0; j < 4; j++)
        acc[nn][j] += f.x * wv[0][j] + f.y * wv[1][j] + f.z * wv[2][j] + f.w * wv[3][j];
    }
  }

#pragma unroll
  for (int j = 0; j < 4; j++) {
    int e = tid + j * 256;
    float gv = g5[e], bv = b5[e];
    float mx = -3.0e38f, sm = 0.f;
#pragma unroll
    for (int nn = 0; nn < TN; nn++) {
      float h = acc[nn][j] * gv + bv;
      h = (h >= 0.f) ? h : 0.2f * h;
      mx = fmaxf(mx, h);
      sm += h;
    }
    pmax[(size_t)blk * 1024 + e] = mx;
    psum[(size_t)blk * 1024 + e] = sm;
  }
}

// ---------------------------------------------------------------------------
// reduce tile partials -> pooled (B, 2048) = [max(1024), mean(1024)]
// ---------------------------------------------------------------------------
__global__ void k_pool(const float* __restrict__ pmax, const float* __restrict__ psum,
                       float* __restrict__ pooled) {
  int i = blockIdx.x * 256 + threadIdx.x;
  if (i >= NBATCH * 1024) return;
  int b = i / 1024, e = i - b * 1024;
  constexpr int NT = NPTS / 16;
  float mx = -3.0e38f, sm = 0.f;
  for (int t = 0; t < NT; t++) {
    mx = fmaxf(mx, pmax[((size_t)b * NT + t) * 1024 + e]);
    sm += psum[((size_t)b * NT + t) * 1024 + e];
  }
  pooled[(size_t)b * 2048 + e] = mx;
  pooled[(size_t)b * 2048 + 1024 + e] = sm * (1.0f / NPTS);
}

// ---------------------------------------------------------------------------
// FC head: 2048->512 (leaky, affine) -> 256 (bias, leaky, affine) -> 40 (+bias)
// one block per batch element.
// ---------------------------------------------------------------------------
__global__ __launch_bounds__(256) void k_head(const float* __restrict__ pooled,
                                              const float* __restrict__ wl1,
                                              const float* __restrict__ g6,
                                              const float* __restrict__ b6,
                                              const float* __restrict__ wl2,
                                              const float* __restrict__ bl2,
                                              const float* __restrict__ g7,
                                              const float* __restrict__ b7,
                                              const float* __restrict__ wl3,
                                              const float* __restrict__ bl3,
                                              float* __restrict__ out) {
  const int b = blockIdx.x;
  const int tid = threadIdx.x;
  __shared__ float pl[2048];
  __shared__ float h1[512];
  __shared__ float h2[256];

  for (int i = tid; i < 2048; i += 256) pl[i] = pooled[(size_t)b * 2048 + i];
  __syncthreads();

  for (int o = tid; o < 512; o += 256) {
    float a = 0.f;
    for (int c = 0; c < 2048; c++) a += pl[c] * wl1[(size_t)c * 512 + o];
    a = a * g6[o] + b6[o];
    h1[o] = (a >= 0.f) ? a : 0.2f * a;
  }
  __syncthreads();

  {
    float a = 0.f;
    for (int c = 0; c < 512; c++) a += h1[c] * wl2[(size_t)c * 256 + tid];
    a = (a + bl2[tid]) * g7[tid] + b7[tid];
    h2[tid] = (a >= 0.f) ? a : 0.2f * a;
  }
  __syncthreads();

  if (tid < 40) {
    float a = bl3[tid];
    for (int c = 0; c < 256; c++) a += h2[c] * wl3[(size_t)c * 40 + tid];
    out[(size_t)b * 40 + tid] = a;
  }
}

// ---------------------------------------------------------------------------
extern "C" void kernel_launch(void* const* d_in, const int* in_sizes, int n_in,
                              void* d_out, int out_size, void* d_ws, size_t ws_size,
                              hipStream_t stream) {
  (void)in_sizes; (void)n_in; (void)out_size; (void)ws_size;
  const float* x   = (const float*)d_in[0];
  const float* w1  = (const float*)d_in[1];
  const float* g1  = (const float*)d_in[2];
  const float* b1  = (const float*)d_in[3];
  const float* w2  = (const float*)d_in[4];
  const float* g2  = (const float*)d_in[5];
  const float* b2  = (const float*)d_in[6];
  const float* w3  = (const float*)d_in[7];
  const float* g3  = (const float*)d_in[8];
  const float* b3  = (const float*)d_in[9];
  const float* w4  = (const float*)d_in[10];
  const float* g4  = (const float*)d_in[11];
  const float* b4  = (const float*)d_in[12];
  const float* w5  = (const float*)d_in[13];
  const float* g5  = (const float*)d_in[14];
  const float* b5  = (const float*)d_in[15];
  const float* wl1 = (const float*)d_in[16];
  const float* g6  = (const float*)d_in[17];
  const float* b6  = (const float*)d_in[18];
  const float* wl2 = (const float*)d_in[19];
  const float* bl2 = (const float*)d_in[20];
  const float* g7  = (const float*)d_in[21];
  const float* b7  = (const float*)d_in[22];
  const float* wl3 = (const float*)d_in[23];
  const float* bl3 = (const float*)d_in[24];

  float* ws = (float*)d_ws;
  size_t off = 0;
  float* h0 = ws + off;   off += (size_t)NBATCH * NPTS * 3;
  float* x1 = ws + off;   off += (size_t)NBATCH * NPTS * 64;
  float* x2 = ws + off;   off += (size_t)NBATCH * NPTS * 64;
  float* x3 = ws + off;   off += (size_t)NBATCH * NPTS * 128;
  float* x4 = ws + off;   off += (size_t)NBATCH * NPTS * 256;
  float* dist = ws + off; off += (size_t)NPTS * NPTS;                 // one batch, reused
  int* knn = (int*)(ws + off); off += (size_t)NBATCH * NPTS * KNN;
  float* pmax = ws + off; off += (size_t)NBATCH * (NPTS / 16) * 1024;
  float* psum = ws + off; off += (size_t)NBATCH * (NPTS / 16) * 1024;
  float* pooled = ws + off;  // + NBATCH*2048

  k_transpose<<<(NBATCH * NPTS * 3 + 255) / 256, 256, 0, stream>>>(x, h0);

  // ---- edge conv 1 (C=3 -> O=64)
  for (int b = 0; b < NBATCH; b++) {
    k_dist<3><<<dim3(NPTS / 64, NPTS / 64), 256, 0, stream>>>(h0 + (size_t)b * NPTS * 3, dist);
    k_topk<<<NPTS, 256, 0, stream>>>(dist, knn + (size_t)b * NPTS * KNN);
  }
  k_edge<3, 64><<<NBATCH * NPTS / 4, 256, 0, stream>>>(h0, knn, w1, g1, b1, x1);

  // ---- edge conv 2 (C=64 -> O=64)
  for (int b = 0; b < NBATCH; b++) {
    k_dist<64><<<dim3(NPTS / 64, NPTS / 64), 256, 0, stream>>>(x1 + (size_t)b * NPTS * 64, dist);
    k_topk<<<NPTS, 256, 0, stream>>>(dist, knn + (size_t)b * NPTS * KNN);
  }
  k_edge<64, 64><<<NBATCH * NPTS / 4, 256, 0, stream>>>(x1, knn, w2, g2, b2, x2);

  // ---- edge conv 3 (C=64 -> O=128)
  for (int b = 0; b < NBATCH; b++) {
    k_dist<64><<<dim3(NPTS / 64, NPTS / 64), 256, 0, stream>>>(x2 + (size_t)b * NPTS * 64, dist);
    k_topk<<<NPTS, 256, 0, stream>>>(dist, knn + (size_t)b * NPTS * KNN);
  }
  k_edge<64, 128><<<NBATCH * NPTS / 2, 256, 0, stream>>>(x2, knn, w3, g3, b3, x3);

  // ---- edge conv 4 (C=128 -> O=256)
  for (int b = 0; b < NBATCH; b++) {
    k_dist<128><<<dim3(NPTS / 64, NPTS / 64), 256, 0, stream>>>(x3 + (size_t)b * NPTS * 128, dist);
    k_topk<<<NPTS, 256, 0, stream>>>(dist, knn + (size_t)b * NPTS * KNN);
  }
  k_edge<128, 256><<<NBATCH * NPTS, 256, 0, stream>>>(x3, knn, w4, g4, b4, x4);

  // ---- point MLP + pooling + head
  k_mlp5<<<NBATCH * (NPTS / 16), 256, 0, stream>>>(x1, x2, x3, x4, w5, g5, b5, pmax, psum);
  k_pool<<<(NBATCH * 1024 + 255) / 256, 256, 0, stream>>>(pmax, psum, pooled);
  k_head<<<NBATCH, 256, 0, stream>>>(pooled, wl1, g6, b6, wl2, bl2, g7, b7, wl3, bl3,
                                     (float*)d_out);
}

// Round 2
// 3047.448 us; speedup vs baseline: 1.0431x; 1.0431x over previous
//
#include <hip/hip_runtime.h>
#include <cstddef>
#include <cstdint>

#define NBATCH 8
#define NPTS   2048
#define KNN    20

// ---------------------------------------------------------------------------
// transpose (B,3,N) -> (B,N,3)
// ---------------------------------------------------------------------------
__global__ void k_transpose(const float* __restrict__ x, float* __restrict__ h0) {
  int i = blockIdx.x * 256 + threadIdx.x;
  if (i >= NBATCH * NPTS * 3) return;
  int c = i % 3;
  int n = (i / 3) % NPTS;
  int b = i / (3 * NPTS);
  h0[i] = x[((size_t)b * 3 + c) * NPTS + n];
}

// ---------------------------------------------------------------------------
// pairwise "distance" pd = 2*dot(x_n,x_m) - |x_n|^2 - |x_m|^2 for ONE batch.
// grid (N/64, N/64), block 256, 4x4 microtile per thread.
// ---------------------------------------------------------------------------
template <int C>
__global__ __launch_bounds__(256) void k_dist(const float* __restrict__ xb,
                                              float* __restrict__ dist) {
  constexpr int PAD = (C % 4 == 0) ? 4 : 1;
  constexpr int S = C + PAD;
  __shared__ __attribute__((aligned(16))) float rows[64 * S];
  __shared__ __attribute__((aligned(16))) float cols[64 * S];
  __shared__ float sq[128];

  const int rt = blockIdx.y, ct = blockIdx.x;
  const int tid = threadIdx.x;

  for (int e = tid; e < 64 * C; e += 256) {
    int i = e / C, c = e - i * C;
    rows[i * S + c] = xb[(size_t)(rt * 64 + i) * C + c];
    cols[i * S + c] = xb[(size_t)(ct * 64 + i) * C + c];
  }
  __syncthreads();
  if (tid < 128) {
    const float* p = (tid < 64) ? (rows + tid * S) : (cols + (tid - 64) * S);
    float s = 0.f;
    for (int c = 0; c < C; c++) s += p[c] * p[c];
    sq[tid] = s;
  }
  __syncthreads();

  const int r0 = (tid >> 4) * 4;
  const int c0 = (tid & 15) * 4;
  float acc[4][4] = {};

  if constexpr (C % 4 == 0) {
    for (int c = 0; c < C; c += 4) {
      float4 ra[4], cb[4];
#pragma unroll
      for (int i = 0; i < 4; i++) ra[i] = *(const float4*)&rows[(r0 + i) * S + c];
#pragma unroll
      for (int j = 0; j < 4; j++) cb[j] = *(const float4*)&cols[(c0 + j) * S + c];
#pragma unroll
      for (int i = 0; i < 4; i++)
#pragma unroll
        for (int j = 0; j < 4; j++)
          acc[i][j] += ra[i].x * cb[j].x + ra[i].y * cb[j].y +
                       ra[i].z * cb[j].z + ra[i].w * cb[j].w;
    }
  } else {
    for (int c = 0; c < C; c++) {
      float ra[4], cb[4];
#pragma unroll
      for (int i = 0; i < 4; i++) ra[i] = rows[(r0 + i) * S + c];
#pragma unroll
      for (int j = 0; j < 4; j++) cb[j] = cols[(c0 + j) * S + c];
#pragma unroll
      for (int i = 0; i < 4; i++)
#pragma unroll
        for (int j = 0; j < 4; j++) acc[i][j] += ra[i] * cb[j];
    }
  }

#pragma unroll
  for (int i = 0; i < 4; i++) {
    float sr = sq[r0 + i];
    float4 v;
    v.x = 2.f * acc[i][0] - sr - sq[64 + c0 + 0];
    v.y = 2.f * acc[i][1] - sr - sq[64 + c0 + 1];
    v.z = 2.f * acc[i][2] - sr - sq[64 + c0 + 2];
    v.w = 2.f * acc[i][3] - sr - sq[64 + c0 + 3];
    *(float4*)&dist[(size_t)(rt * 64 + r0 + i) * NPTS + ct * 64 + c0] = v;
  }
}

// ---------------------------------------------------------------------------
// top-20 per row (one batch). block per row, candidates register-resident.
// reg i of thread t holds element index i*256+t; tie-break = lowest index
// (strict > over ascending i keeps lowest; cross-thread compare is explicit).
// ---------------------------------------------------------------------------
__global__ __launch_bounds__(256) void k_topk(const float* __restrict__ dist,
                                              int* __restrict__ idx_out) {
  const int n = blockIdx.x;
  const float* drow = dist + (size_t)n * NPTS;
  const int tid = threadIdx.x;
  __shared__ float rv[4];
  __shared__ int ri[4];
  __shared__ int win;

  float v[8];
#pragma unroll
  for (int i = 0; i < 8; i++) v[i] = drow[tid + i * 256];

  for (int k = 0; k < KNN; k++) {
    float bv = v[0];
    int bl = 0;
#pragma unroll
    for (int i = 1; i < 8; i++)
      if (v[i] > bv) { bv = v[i]; bl = i; }
    int bi = bl * 256 + tid;
#pragma unroll
    for (int off = 32; off > 0; off >>= 1) {
      float ov = __shfl_down(bv, off);
      int oi = __shfl_down(bi, off);
      if (ov > bv || (ov == bv && oi < bi)) { bv = ov; bi = oi; }
    }
    if ((tid & 63) == 0) { rv[tid >> 6] = bv; ri[tid >> 6] = bi; }
    __syncthreads();
    if (tid == 0) {
#pragma unroll
      for (int w = 1; w < 4; w++)
        if (rv[w] > bv || (rv[w] == bv && ri[w] < bi)) { bv = rv[w]; bi = ri[w]; }
      idx_out[n * KNN + k] = bi;
      win = bi;
    }
    __syncthreads();
    int wi = win;
    if ((wi & 255) == tid) v[wi >> 8] = -3.0e38f;
  }
}

// ---------------------------------------------------------------------------
// edge conv: out[b,n,o] = max_k leaky((feat@w)*g + b), feat=[nb-ctr, ctr].
// ---------------------------------------------------------------------------
template <int C, int O>
__global__ __launch_bounds__(256) void k_edge(const float* __restrict__ x,
                                              const int* __restrict__ knn,
                                              const float* __restrict__ w,
                                              const float* __restrict__ g,
                                              const float* __restrict__ bta,
                                              float* __restrict__ out) {
  constexpr int NPB = 256 / O;
  __shared__ __attribute__((aligned(16))) float nbd[NPB * KNN * C];
  __shared__ float ctr[NPB * C];

  const int blk = blockIdx.x;
  const int b = blk / (NPTS / NPB);
  const int n0 = (blk % (NPTS / NPB)) * NPB;
  const int tid = threadIdx.x;
  const float* xb = x + (size_t)b * NPTS * C;

  for (int e = tid; e < NPB * C; e += 256) {
    int p = e / C, c = e - p * C;
    ctr[e] = xb[(size_t)(n0 + p) * C + c];
  }
  __syncthreads();
  for (int e = tid; e < NPB * KNN * C; e += 256) {
    int c = e % C;
    int t = e / C;
    int k = t % KNN;
    int p = t / KNN;
    int m = knn[(size_t)(b * NPTS + n0 + p) * KNN + k];
    nbd[e] = xb[(size_t)m * C + c] - ctr[p * C + c];
  }
  __syncthreads();

  const int p = tid / O;
  const int o = tid - p * O;

  float t0 = 0.f;
  for (int c = 0; c < C; c++) t0 += ctr[p * C + c] * w[(C + c) * O + o];

  float acc[KNN];
#pragma unroll
  for (int k = 0; k < KNN; k++) acc[k] = t0;

  const float* nb_p = nbd + p * KNN * C;
  if constexpr (C % 4 == 0) {
    for (int c = 0; c < C; c += 4) {
      float wv0 = w[(c + 0) * O + o];
      float wv1 = w[(c + 1) * O + o];
      float wv2 = w[(c + 2) * O + o];
      float wv3 = w[(c + 3) * O + o];
#pragma unroll
      for (int k = 0; k < KNN; k++) {
        float4 f = *(const float4*)&nb_p[k * C + c];
        acc[k] += f.x * wv0 + f.y * wv1 + f.z * wv2 + f.w * wv3;
      }
    }
  } else {
    for (int c = 0; c < C; c++) {
      float wv = w[c * O + o];
#pragma unroll
      for (int k = 0; k < KNN; k++) acc[k] += nb_p[k * C + c] * wv;
    }
  }

  const float gv = g[o], bv = bta[o];
  float mx = -3.0e38f;
#pragma unroll
  for (int k = 0; k < KNN; k++) {
    float h = acc[k] * gv + bv;
    h = (h >= 0.f) ? h : 0.2f * h;
    mx = fmaxf(mx, h);
  }
  out[(size_t)(b * NPTS + n0 + p) * O + o] = mx;
}

// ---------------------------------------------------------------------------
// point MLP 512->1024 as tiled fp32 GEMM. M=16384 pts, N=1024, K=512.
// 128x128 tile per block (256 thr, 8x8 microtile), K-tile 16, both operands
// LDS-staged. Epilogue: affine + leaky + max/sum pool over the 128-pt tile.
// grid: (128 m-tiles, 8 n-tiles). 128 | 2048 so tiles never cross batches.
// ---------------------------------------------------------------------------
__global__ __launch_bounds__(256) void k_mlp5(const float* __restrict__ x1,
                                              const float* __restrict__ x2,
                                              const float* __restrict__ x3,
                                              const float* __restrict__ x4,
                                              const float* __restrict__ w5,
                                              const float* __restrict__ g5,
                                              const float* __restrict__ b5,
                                              float* __restrict__ pmax,
                                              float* __restrict__ psum) {
  constexpr int TM = 128, TN = 128, TK = 16, PAD = 4;
  __shared__ __attribute__((aligned(16))) float As[TK][TM + PAD];
  __shared__ __attribute__((aligned(16))) float Bs[TK][TN + PAD];

  const int mt = blockIdx.x;   // 0..127
  const int nt = blockIdx.y;   // 0..7
  const int tid = threadIdx.x;
  const int tx = tid & 15, ty = tid >> 4;
  const size_t m0 = (size_t)mt * TM;
  const int n0 = nt * TN;

  float acc[8][8] = {};

  for (int kt = 0; kt < 512; kt += TK) {
    // pick the source feature map for this 16-wide k-slab (slab never spans two)
    const float* src;
    int cs, cw;
    if (kt < 64)       { src = x1; cs = kt;       cw = 64;  }
    else if (kt < 128) { src = x2; cs = kt - 64;  cw = 64;  }
    else if (kt < 256) { src = x3; cs = kt - 128; cw = 128; }
    else               { src = x4; cs = kt - 256; cw = 256; }
    // A tile: 128 pts x 16 k, k-fast for 16-float coalesced runs
#pragma unroll
    for (int e = 0; e < 8; e++) {
      int idx = tid + e * 256;
      int m = idx >> 4, k = idx & 15;
      As[k][m] = src[(m0 + m) * cw + cs + k];
    }
    // B tile: 16 k x 128 n, n-fast fully coalesced
#pragma unroll
    for (int e = 0; e < 8; e++) {
      int idx = tid + e * 256;
      int k = idx >> 7, nn = idx & 127;
      Bs[k][nn] = w5[(size_t)(kt + k) * 1024 + n0 + nn];
    }
    __syncthreads();
#pragma unroll
    for (int kk = 0; kk < TK; kk++) {
      float4 a0 = *(const float4*)&As[kk][ty * 8];
      float4 a1 = *(const float4*)&As[kk][ty * 8 + 4];
      float4 c0 = *(const float4*)&Bs[kk][tx * 8];
      float4 c1 = *(const float4*)&Bs[kk][tx * 8 + 4];
      float av[8] = {a0.x, a0.y, a0.z, a0.w, a1.x, a1.y, a1.z, a1.w};
      float bb[8] = {c0.x, c0.y, c0.z, c0.w, c1.x, c1.y, c1.z, c1.w};
#pragma unroll
      for (int i = 0; i < 8; i++)
#pragma unroll
        for (int j = 0; j < 8; j++) acc[i][j] += av[i] * bb[j];
    }
    __syncthreads();
  }

  // epilogue: affine + leaky, pool over this thread's 8 rows
  float gv[8], bv[8], mx[8], sm[8];
#pragma unroll
  for (int j = 0; j < 8; j++) {
    gv[j] = g5[n0 + tx * 8 + j];
    bv[j] = b5[n0 + tx * 8 + j];
    mx[j] = -3.0e38f;
    sm[j] = 0.f;
  }
#pragma unroll
  for (int i = 0; i < 8; i++)
#pragma unroll
    for (int j = 0; j < 8; j++) {
      float h = acc[i][j] * gv[j] + bv[j];
      h = (h >= 0.f) ? h : 0.2f * h;
      mx[j] = fmaxf(mx[j], h);
      sm[j] += h;
    }

  // cross-ty reduction via LDS (reuse As = max, Bs = sum)
#pragma unroll
  for (int j = 0; j < 8; j++) {
    As[ty][tx * 8 + j] = mx[j];
    Bs[ty][tx * 8 + j] = sm[j];
  }
  __syncthreads();
  for (int s = 8; s > 0; s >>= 1) {
    if (ty < s) {
#pragma unroll
      for (int j = 0; j < 8; j++) {
        As[ty][tx * 8 + j] = fmaxf(As[ty][tx * 8 + j], As[ty + s][tx * 8 + j]);
        Bs[ty][tx * 8 + j] += Bs[ty + s][tx * 8 + j];
      }
    }
    __syncthreads();
  }
  if (ty == 0) {
#pragma unroll
    for (int j = 0; j < 8; j++) {
      pmax[(size_t)mt * 1024 + n0 + tx * 8 + j] = As[0][tx * 8 + j];
      psum[(size_t)mt * 1024 + n0 + tx * 8 + j] = Bs[0][tx * 8 + j];
    }
  }
}

// ---------------------------------------------------------------------------
// reduce tile partials -> pooled (B, 2048) = [max(1024), mean(1024)]
// ---------------------------------------------------------------------------
__global__ void k_pool(const float* __restrict__ pmax, const float* __restrict__ psum,
                       float* __restrict__ pooled) {
  int i = blockIdx.x * 256 + threadIdx.x;
  if (i >= NBATCH * 1024) return;
  int b = i / 1024, e = i - b * 1024;
  constexpr int NT = NPTS / 128;  // 16 m-tiles per batch
  float mx = -3.0e38f, sm = 0.f;
  for (int t = 0; t < NT; t++) {
    mx = fmaxf(mx, pmax[((size_t)b * NT + t) * 1024 + e]);
    sm += psum[((size_t)b * NT + t) * 1024 + e];
  }
  pooled[(size_t)b * 2048 + e] = mx;
  pooled[(size_t)b * 2048 + 1024 + e] = sm * (1.0f / NPTS);
}

// ---------------------------------------------------------------------------
// FC head: 2048->512 (leaky, affine) -> 256 (bias, leaky, affine) -> 40 (+bias)
// ---------------------------------------------------------------------------
__global__ __launch_bounds__(256) void k_head(const float* __restrict__ pooled,
                                              const float* __restrict__ wl1,
                                              const float* __restrict__ g6,
                                              const float* __restrict__ b6,
                                              const float* __restrict__ wl2,
                                              const float* __restrict__ bl2,
                                              const float* __restrict__ g7,
                                              const float* __restrict__ b7,
                                              const float* __restrict__ wl3,
                                              const float* __restrict__ bl3,
                                              float* __restrict__ out) {
  const int b = blockIdx.x;
  const int tid = threadIdx.x;
  __shared__ float pl[2048];
  __shared__ float h1[512];
  __shared__ float h2[256];

  for (int i = tid; i < 2048; i += 256) pl[i] = pooled[(size_t)b * 2048 + i];
  __syncthreads();

  for (int o = tid; o < 512; o += 256) {
    float a = 0.f;
    for (int c = 0; c < 2048; c++) a += pl[c] * wl1[(size_t)c * 512 + o];
    a = a * g6[o] + b6[o];
    h1[o] = (a >= 0.f) ? a : 0.2f * a;
  }
  __syncthreads();

  {
    float a = 0.f;
    for (int c = 0; c < 512; c++) a += h1[c] * wl2[(size_t)c * 256 + tid];
    a = (a + bl2[tid]) * g7[tid] + b7[tid];
    h2[tid] = (a >= 0.f) ? a : 0.2f * a;
  }
  __syncthreads();

  if (tid < 40) {
    float a = bl3[tid];
    for (int c = 0; c < 256; c++) a += h2[c] * wl3[(size_t)c * 40 + tid];
    out[(size_t)b * 40 + tid] = a;
  }
}

// ---------------------------------------------------------------------------
extern "C" void kernel_launch(void* const* d_in, const int* in_sizes, int n_in,
                              void* d_out, int out_size, void* d_ws, size_t ws_size,
                              hipStream_t stream) {
  (void)in_sizes; (void)n_in; (void)out_size; (void)ws_size;
  const float* x   = (const float*)d_in[0];
  const float* w1  = (const float*)d_in[1];
  const float* g1  = (const float*)d_in[2];
  const float* b1  = (const float*)d_in[3];
  const float* w2  = (const float*)d_in[4];
  const float* g2  = (const float*)d_in[5];
  const float* b2  = (const float*)d_in[6];
  const float* w3  = (const float*)d_in[7];
  const float* g3  = (const float*)d_in[8];
  const float* b3  = (const float*)d_in[9];
  const float* w4  = (const float*)d_in[10];
  const float* g4  = (const float*)d_in[11];
  const float* b4  = (const float*)d_in[12];
  const float* w5  = (const float*)d_in[13];
  const float* g5  = (const float*)d_in[14];
  const float* b5  = (const float*)d_in[15];
  const float* wl1 = (const float*)d_in[16];
  const float* g6  = (const float*)d_in[17];
  const float* b6  = (const float*)d_in[18];
  const float* wl2 = (const float*)d_in[19];
  const float* bl2 = (const float*)d_in[20];
  const float* g7  = (const float*)d_in[21];
  const float* b7  = (const float*)d_in[22];
  const float* wl3 = (const float*)d_in[23];
  const float* bl3 = (const float*)d_in[24];

  float* ws = (float*)d_ws;
  size_t off = 0;
  float* h0 = ws + off;   off += (size_t)NBATCH * NPTS * 3;
  float* x1 = ws + off;   off += (size_t)NBATCH * NPTS * 64;
  float* x2 = ws + off;   off += (size_t)NBATCH * NPTS * 64;
  float* x3 = ws + off;   off += (size_t)NBATCH * NPTS * 128;
  float* x4 = ws + off;   off += (size_t)NBATCH * NPTS * 256;
  float* dist = ws + off; off += (size_t)NPTS * NPTS;                 // one batch, reused
  int* knn = (int*)(ws + off); off += (size_t)NBATCH * NPTS * KNN;
  float* pmax = ws + off; off += (size_t)(NPTS / 128) * NBATCH * 1024;
  float* psum = ws + off; off += (size_t)(NPTS / 128) * NBATCH * 1024;
  float* pooled = ws + off;  // + NBATCH*2048

  k_transpose<<<(NBATCH * NPTS * 3 + 255) / 256, 256, 0, stream>>>(x, h0);

  // ---- edge conv 1 (C=3 -> O=64)
  for (int b = 0; b < NBATCH; b++) {
    k_dist<3><<<dim3(NPTS / 64, NPTS / 64), 256, 0, stream>>>(h0 + (size_t)b * NPTS * 3, dist);
    k_topk<<<NPTS, 256, 0, stream>>>(dist, knn + (size_t)b * NPTS * KNN);
  }
  k_edge<3, 64><<<NBATCH * NPTS / 4, 256, 0, stream>>>(h0, knn, w1, g1, b1, x1);

  // ---- edge conv 2 (C=64 -> O=64)
  for (int b = 0; b < NBATCH; b++) {
    k_dist<64><<<dim3(NPTS / 64, NPTS / 64), 256, 0, stream>>>(x1 + (size_t)b * NPTS * 64, dist);
    k_topk<<<NPTS, 256, 0, stream>>>(dist, knn + (size_t)b * NPTS * KNN);
  }
  k_edge<64, 64><<<NBATCH * NPTS / 4, 256, 0, stream>>>(x1, knn, w2, g2, b2, x2);

  // ---- edge conv 3 (C=64 -> O=128)
  for (int b = 0; b < NBATCH; b++) {
    k_dist<64><<<dim3(NPTS / 64, NPTS / 64), 256, 0, stream>>>(x2 + (size_t)b * NPTS * 64, dist);
    k_topk<<<NPTS, 256, 0, stream>>>(dist, knn + (size_t)b * NPTS * KNN);
  }
  k_edge<64, 128><<<NBATCH * NPTS / 2, 256, 0, stream>>>(x2, knn, w3, g3, b3, x3);

  // ---- edge conv 4 (C=128 -> O=256)
  for (int b = 0; b < NBATCH; b++) {
    k_dist<128><<<dim3(NPTS / 64, NPTS / 64), 256, 0, stream>>>(x3 + (size_t)b * NPTS * 128, dist);
    k_topk<<<NPTS, 256, 0, stream>>>(dist, knn + (size_t)b * NPTS * KNN);
  }
  k_edge<128, 256><<<NBATCH * NPTS, 256, 0, stream>>>(x3, knn, w4, g4, b4, x4);

  // ---- point MLP (tiled GEMM) + pooling + head
  k_mlp5<<<dim3(NBATCH * NPTS / 128, 8), 256, 0, stream>>>(x1, x2, x3, x4, w5, g5, b5,
                                                           pmax, psum);
  k_pool<<<(NBATCH * 1024 + 255) / 256, 256, 0, stream>>>(pmax, psum, pooled);
  k_head<<<NBATCH, 256, 0, stream>>>(pooled, wl1, g6, b6, wl2, bl2, g7, b7, wl3, bl3,
                                     (float*)d_out);
}

// Round 3
// 2962.855 us; speedup vs baseline: 1.0728x; 1.0286x over previous
//
#include <hip/hip_runtime.h>
#include <cstddef>
#include <cstdint>

#define NBATCH 8
#define NPTS   2048
#define KNN    20

// ---------------------------------------------------------------------------
// transpose (B,3,N) -> (B,N,3)
// ---------------------------------------------------------------------------
__global__ void k_transpose(const float* __restrict__ x, float* __restrict__ h0) {
  int i = blockIdx.x * 256 + threadIdx.x;
  if (i >= NBATCH * NPTS * 3) return;
  int c = i % 3;
  int n = (i / 3) % NPTS;
  int b = i / (3 * NPTS);
  h0[i] = x[((size_t)b * 3 + c) * NPTS + n];
}

// ---------------------------------------------------------------------------
// pairwise "distance" pd = 2*dot(x_n,x_m) - |x_n|^2 - |x_m|^2 for ONE batch.
// grid (N/64, N/64), block 256, 4x4 microtile per thread.
// ---------------------------------------------------------------------------
template <int C>
__global__ __launch_bounds__(256) void k_dist(const float* __restrict__ xb,
                                              float* __restrict__ dist) {
  constexpr int PAD = (C % 4 == 0) ? 4 : 1;
  constexpr int S = C + PAD;
  __shared__ __attribute__((aligned(16))) float rows[64 * S];
  __shared__ __attribute__((aligned(16))) float cols[64 * S];
  __shared__ float sq[128];

  const int rt = blockIdx.y, ct = blockIdx.x;
  const int tid = threadIdx.x;

  for (int e = tid; e < 64 * C; e += 256) {
    int i = e / C, c = e - i * C;
    rows[i * S + c] = xb[(size_t)(rt * 64 + i) * C + c];
    cols[i * S + c] = xb[(size_t)(ct * 64 + i) * C + c];
  }
  __syncthreads();
  if (tid < 128) {
    const float* p = (tid < 64) ? (rows + tid * S) : (cols + (tid - 64) * S);
    float s = 0.f;
    for (int c = 0; c < C; c++) s += p[c] * p[c];
    sq[tid] = s;
  }
  __syncthreads();

  const int r0 = (tid >> 4) * 4;
  const int c0 = (tid & 15) * 4;
  float acc[4][4] = {};

  if constexpr (C % 4 == 0) {
    for (int c = 0; c < C; c += 4) {
      float4 ra[4], cb[4];
#pragma unroll
      for (int i = 0; i < 4; i++) ra[i] = *(const float4*)&rows[(r0 + i) * S + c];
#pragma unroll
      for (int j = 0; j < 4; j++) cb[j] = *(const float4*)&cols[(c0 + j) * S + c];
#pragma unroll
      for (int i = 0; i < 4; i++)
#pragma unroll
        for (int j = 0; j < 4; j++)
          acc[i][j] += ra[i].x * cb[j].x + ra[i].y * cb[j].y +
                       ra[i].z * cb[j].z + ra[i].w * cb[j].w;
    }
  } else {
    for (int c = 0; c < C; c++) {
      float ra[4], cb[4];
#pragma unroll
      for (int i = 0; i < 4; i++) ra[i] = rows[(r0 + i) * S + c];
#pragma unroll
      for (int j = 0; j < 4; j++) cb[j] = cols[(c0 + j) * S + c];
#pragma unroll
      for (int i = 0; i < 4; i++)
#pragma unroll
        for (int j = 0; j < 4; j++) acc[i][j] += ra[i] * cb[j];
    }
  }

#pragma unroll
  for (int i = 0; i < 4; i++) {
    float sr = sq[r0 + i];
    float4 v;
    v.x = 2.f * acc[i][0] - sr - sq[64 + c0 + 0];
    v.y = 2.f * acc[i][1] - sr - sq[64 + c0 + 1];
    v.z = 2.f * acc[i][2] - sr - sq[64 + c0 + 2];
    v.w = 2.f * acc[i][3] - sr - sq[64 + c0 + 3];
    *(float4*)&dist[(size_t)(rt * 64 + r0 + i) * NPTS + ct * 64 + c0] = v;
  }
}

// ---------------------------------------------------------------------------
// top-20 per row (one batch). block per row. Phase 1: each wave builds its own
// descending top-20 of its 512 elements entirely with shuffles (no barriers).
// Phase 2: one thread merges the 4 sorted lists. Tie-break: lowest index.
// ---------------------------------------------------------------------------
__global__ __launch_bounds__(256) void k_topk(const float* __restrict__ dist,
                                              int* __restrict__ idx_out) {
  const int n = blockIdx.x;
  const float* drow = dist + (size_t)n * NPTS;
  const int tid = threadIdx.x;
  const int lane = tid & 63;
  const int wid = tid >> 6;
  __shared__ float cv[4][KNN];
  __shared__ int ci[4][KNN];

  float v[8];
#pragma unroll
  for (int i = 0; i < 8; i++) v[i] = drow[tid + i * 256];

  for (int k = 0; k < KNN; k++) {
    float bv = v[0];
    int bl = 0;
#pragma unroll
    for (int i = 1; i < 8; i++)
      if (v[i] > bv) { bv = v[i]; bl = i; }   // ascending i keeps lowest index
    int bi = bl * 256 + tid;
#pragma unroll
    for (int off = 32; off > 0; off >>= 1) {
      float ov = __shfl_down(bv, off);
      int oi = __shfl_down(bi, off);
      if (ov > bv || (ov == bv && oi < bi)) { bv = ov; bi = oi; }
    }
    bv = __shfl(bv, 0);
    bi = __shfl(bi, 0);
    if (lane == 0) { cv[wid][k] = bv; ci[wid][k] = bi; }
    if ((bi & 255) == tid) v[bi >> 8] = -3.0e38f;  // owner invalidates
  }
  __syncthreads();

  if (tid == 0) {
    int ptr[4] = {0, 0, 0, 0};
    for (int k = 0; k < KNN; k++) {
      float bb = -3.4e38f;
      int bi = 0x7fffffff, bw = 0;
#pragma unroll
      for (int w = 0; w < 4; w++) {
        if (ptr[w] < KNN) {
          float vv = cv[w][ptr[w]];
          int ii = ci[w][ptr[w]];
          if (vv > bb || (vv == bb && ii < bi)) { bb = vv; bi = ii; bw = w; }
        }
      }
      idx_out[n * KNN + k] = bi;
      ptr[bw]++;
    }
  }
}

// ---------------------------------------------------------------------------
// edge conv: out[b,n,o] = max_k leaky((feat@w)*g + b), feat=[nb-ctr, ctr].
// Wave per point (4 points/block); thread computes JO=O/64 output channels.
// Per 4-wide c-step: KNN ds_read_b128 (wave-broadcast) + 4*JO w loads feed
// 4*KNN*JO FMAs.
// ---------------------------------------------------------------------------
template <int C, int O>
__global__ __launch_bounds__(256) void k_edge(const float* __restrict__ x,
                                              const int* __restrict__ knn,
                                              const float* __restrict__ w,
                                              const float* __restrict__ g,
                                              const float* __restrict__ bta,
                                              float* __restrict__ out) {
  constexpr int JO = O / 64;
  constexpr int NPB = 4;
  __shared__ __attribute__((aligned(16))) float nbd[NPB * KNN * C];
  __shared__ __attribute__((aligned(16))) float ctr[NPB * C];

  const int blk = blockIdx.x;
  const int b = blk / (NPTS / NPB);
  const int n0 = (blk % (NPTS / NPB)) * NPB;
  const int tid = threadIdx.x;
  const int lane = tid & 63;
  const int p = tid >> 6;
  const float* xb = x + (size_t)b * NPTS * C;

  for (int e = tid; e < NPB * C; e += 256) {
    int pp = e / C, c = e - pp * C;
    ctr[e] = xb[(size_t)(n0 + pp) * C + c];
  }
  __syncthreads();
  for (int e = tid; e < NPB * KNN * C; e += 256) {
    int c = e % C;
    int t = e / C;
    int k = t % KNN;
    int pp = t / KNN;
    int m = knn[(size_t)(b * NPTS + n0 + pp) * KNN + k];
    nbd[e] = xb[(size_t)m * C + c] - ctr[pp * C + c];
  }
  __syncthreads();

  float acc[KNN][JO];
  {
    float t0[JO] = {};
    for (int c = 0; c < C; c++) {
      float cvv = ctr[p * C + c];
#pragma unroll
      for (int j = 0; j < JO; j++) t0[j] += cvv * w[(size_t)(C + c) * O + j * 64 + lane];
    }
#pragma unroll
    for (int k = 0; k < KNN; k++)
#pragma unroll
      for (int j = 0; j < JO; j++) acc[k][j] = t0[j];
  }

  const float* nb_p = nbd + p * KNN * C;
  if constexpr (C % 4 == 0) {
    for (int c = 0; c < C; c += 4) {
      float wv[4][JO];
#pragma unroll
      for (int cc = 0; cc < 4; cc++)
#pragma unroll
        for (int j = 0; j < JO; j++)
          wv[cc][j] = w[(size_t)(c + cc) * O + j * 64 + lane];
#pragma unroll
      for (int k = 0; k < KNN; k++) {
        float4 f = *(const float4*)&nb_p[k * C + c];
#pragma unroll
        for (int j = 0; j < JO; j++)
          acc[k][j] += f.x * wv[0][j] + f.y * wv[1][j] + f.z * wv[2][j] + f.w * wv[3][j];
      }
    }
  } else {
    for (int c = 0; c < C; c++) {
      float wv[JO];
#pragma unroll
      for (int j = 0; j < JO; j++) wv[j] = w[(size_t)c * O + j * 64 + lane];
#pragma unroll
      for (int k = 0; k < KNN; k++) {
        float f = nb_p[k * C + c];
#pragma unroll
        for (int j = 0; j < JO; j++) acc[k][j] += f * wv[j];
      }
    }
  }

#pragma unroll
  for (int j = 0; j < JO; j++) {
    const float gv = g[j * 64 + lane], bv = bta[j * 64 + lane];
    float mx = -3.0e38f;
#pragma unroll
    for (int k = 0; k < KNN; k++) {
      float h = acc[k][j] * gv + bv;
      h = (h >= 0.f) ? h : 0.2f * h;
      mx = fmaxf(mx, h);
    }
    out[(size_t)(b * NPTS + n0 + p) * O + j * 64 + lane] = mx;
  }
}

// ---------------------------------------------------------------------------
// point MLP 512->1024 as tiled fp32 GEMM. M=16384 pts, N=1024, K=512.
// 128x128 tile per block (256 thr, 8x8 microtile), K-tile 16.
// Epilogue: affine + leaky + max/sum pool over the 128-pt tile.
// ---------------------------------------------------------------------------
__global__ __launch_bounds__(256) void k_mlp5(const float* __restrict__ x1,
                                              const float* __restrict__ x2,
                                              const float* __restrict__ x3,
                                              const float* __restrict__ x4,
                                              const float* __restrict__ w5,
                                              const float* __restrict__ g5,
                                              const float* __restrict__ b5,
                                              float* __restrict__ pmax,
                                              float* __restrict__ psum) {
  constexpr int TM = 128, TN = 128, TK = 16, PAD = 4;
  __shared__ __attribute__((aligned(16))) float As[TK][TM + PAD];
  __shared__ __attribute__((aligned(16))) float Bs[TK][TN + PAD];

  const int mt = blockIdx.x;
  const int nt = blockIdx.y;
  const int tid = threadIdx.x;
  const int tx = tid & 15, ty = tid >> 4;
  const size_t m0 = (size_t)mt * TM;
  const int n0 = nt * TN;

  float acc[8][8] = {};

  for (int kt = 0; kt < 512; kt += TK) {
    const float* src;
    int cs, cw;
    if (kt < 64)       { src = x1; cs = kt;       cw = 64;  }
    else if (kt < 128) { src = x2; cs = kt - 64;  cw = 64;  }
    else if (kt < 256) { src = x3; cs = kt - 128; cw = 128; }
    else               { src = x4; cs = kt - 256; cw = 256; }
#pragma unroll
    for (int e = 0; e < 8; e++) {
      int idx = tid + e * 256;
      int m = idx >> 4, k = idx & 15;
      As[k][m] = src[(m0 + m) * cw + cs + k];
    }
#pragma unroll
    for (int e = 0; e < 8; e++) {
      int idx = tid + e * 256;
      int k = idx >> 7, nn = idx & 127;
      Bs[k][nn] = w5[(size_t)(kt + k) * 1024 + n0 + nn];
    }
    __syncthreads();
#pragma unroll
    for (int kk = 0; kk < TK; kk++) {
      float4 a0 = *(const float4*)&As[kk][ty * 8];
      float4 a1 = *(const float4*)&As[kk][ty * 8 + 4];
      float4 c0 = *(const float4*)&Bs[kk][tx * 8];
      float4 c1 = *(const float4*)&Bs[kk][tx * 8 + 4];
      float av[8] = {a0.x, a0.y, a0.z, a0.w, a1.x, a1.y, a1.z, a1.w};
      float bb[8] = {c0.x, c0.y, c0.z, c0.w, c1.x, c1.y, c1.z, c1.w};
#pragma unroll
      for (int i = 0; i < 8; i++)
#pragma unroll
        for (int j = 0; j < 8; j++) acc[i][j] += av[i] * bb[j];
    }
    __syncthreads();
  }

  float gv[8], bv[8], mx[8], sm[8];
#pragma unroll
  for (int j = 0; j < 8; j++) {
    gv[j] = g5[n0 + tx * 8 + j];
    bv[j] = b5[n0 + tx * 8 + j];
    mx[j] = -3.0e38f;
    sm[j] = 0.f;
  }
#pragma unroll
  for (int i = 0; i < 8; i++)
#pragma unroll
    for (int j = 0; j < 8; j++) {
      float h = acc[i][j] * gv[j] + bv[j];
      h = (h >= 0.f) ? h : 0.2f * h;
      mx[j] = fmaxf(mx[j], h);
      sm[j] += h;
    }

#pragma unroll
  for (int j = 0; j < 8; j++) {
    As[ty][tx * 8 + j] = mx[j];
    Bs[ty][tx * 8 + j] = sm[j];
  }
  __syncthreads();
  for (int s = 8; s > 0; s >>= 1) {
    if (ty < s) {
#pragma unroll
      for (int j = 0; j < 8; j++) {
        As[ty][tx * 8 + j] = fmaxf(As[ty][tx * 8 + j], As[ty + s][tx * 8 + j]);
        Bs[ty][tx * 8 + j] += Bs[ty + s][tx * 8 + j];
      }
    }
    __syncthreads();
  }
  if (ty == 0) {
#pragma unroll
    for (int j = 0; j < 8; j++) {
      pmax[(size_t)mt * 1024 + n0 + tx * 8 + j] = As[0][tx * 8 + j];
      psum[(size_t)mt * 1024 + n0 + tx * 8 + j] = Bs[0][tx * 8 + j];
    }
  }
}

// ---------------------------------------------------------------------------
// reduce tile partials -> pooled (B, 2048) = [max(1024), mean(1024)]
// ---------------------------------------------------------------------------
__global__ void k_pool(const float* __restrict__ pmax, const float* __restrict__ psum,
                       float* __restrict__ pooled) {
  int i = blockIdx.x * 256 + threadIdx.x;
  if (i >= NBATCH * 1024) return;
  int b = i / 1024, e = i - b * 1024;
  constexpr int NT = NPTS / 128;
  float mx = -3.0e38f, sm = 0.f;
  for (int t = 0; t < NT; t++) {
    mx = fmaxf(mx, pmax[((size_t)b * NT + t) * 1024 + e]);
    sm += psum[((size_t)b * NT + t) * 1024 + e];
  }
  pooled[(size_t)b * 2048 + e] = mx;
  pooled[(size_t)b * 2048 + 1024 + e] = sm * (1.0f / NPTS);
}

// ---------------------------------------------------------------------------
// FC head: 2048->512 (leaky, affine) -> 256 (bias, leaky, affine) -> 40 (+bias)
// ---------------------------------------------------------------------------
__global__ __launch_bounds__(256) void k_head(const float* __restrict__ pooled,
                                              const float* __restrict__ wl1,
                                              const float* __restrict__ g6,
                                              const float* __restrict__ b6,
                                              const float* __restrict__ wl2,
                                              const float* __restrict__ bl2,
                                              const float* __restrict__ g7,
                                              const float* __restrict__ b7,
                                              const float* __restrict__ wl3,
                                              const float* __restrict__ bl3,
                                              float* __restrict__ out) {
  const int b = blockIdx.x;
  const int tid = threadIdx.x;
  __shared__ float pl[2048];
  __shared__ float h1[512];
  __shared__ float h2[256];

  for (int i = tid; i < 2048; i += 256) pl[i] = pooled[(size_t)b * 2048 + i];
  __syncthreads();

  for (int o = tid; o < 512; o += 256) {
    float a = 0.f;
    for (int c = 0; c < 2048; c++) a += pl[c] * wl1[(size_t)c * 512 + o];
    a = a * g6[o] + b6[o];
    h1[o] = (a >= 0.f) ? a : 0.2f * a;
  }
  __syncthreads();

  {
    float a = 0.f;
    for (int c = 0; c < 512; c++) a += h1[c] * wl2[(size_t)c * 256 + tid];
    a = (a + bl2[tid]) * g7[tid] + b7[tid];
    h2[tid] = (a >= 0.f) ? a : 0.2f * a;
  }
  __syncthreads();

  if (tid < 40) {
    float a = bl3[tid];
    for (int c = 0; c < 256; c++) a += h2[c] * wl3[(size_t)c * 40 + tid];
    out[(size_t)b * 40 + tid] = a;
  }
}

// ---------------------------------------------------------------------------
extern "C" void kernel_launch(void* const* d_in, const int* in_sizes, int n_in,
                              void* d_out, int out_size, void* d_ws, size_t ws_size,
                              hipStream_t stream) {
  (void)in_sizes; (void)n_in; (void)out_size; (void)ws_size;
  const float* x   = (const float*)d_in[0];
  const float* w1  = (const float*)d_in[1];
  const float* g1  = (const float*)d_in[2];
  const float* b1  = (const float*)d_in[3];
  const float* w2  = (const float*)d_in[4];
  const float* g2  = (const float*)d_in[5];
  const float* b2  = (const float*)d_in[6];
  const float* w3  = (const float*)d_in[7];
  const float* g3  = (const float*)d_in[8];
  const float* b3  = (const float*)d_in[9];
  const float* w4  = (const float*)d_in[10];
  const float* g4  = (const float*)d_in[11];
  const float* b4  = (const float*)d_in[12];
  const float* w5  = (const float*)d_in[13];
  const float* g5  = (const float*)d_in[14];
  const float* b5  = (const float*)d_in[15];
  const float* wl1 = (const float*)d_in[16];
  const float* g6  = (const float*)d_in[17];
  const float* b6  = (const float*)d_in[18];
  const float* wl2 = (const float*)d_in[19];
  const float* bl2 = (const float*)d_in[20];
  const float* g7  = (const float*)d_in[21];
  const float* b7  = (const float*)d_in[22];
  const float* wl3 = (const float*)d_in[23];
  const float* bl3 = (const float*)d_in[24];

  float* ws = (float*)d_ws;
  size_t off = 0;
  float* h0 = ws + off;   off += (size_t)NBATCH * NPTS * 3;
  float* x1 = ws + off;   off += (size_t)NBATCH * NPTS * 64;
  float* x2 = ws + off;   off += (size_t)NBATCH * NPTS * 64;
  float* x3 = ws + off;   off += (size_t)NBATCH * NPTS * 128;
  float* x4 = ws + off;   off += (size_t)NBATCH * NPTS * 256;
  float* dist = ws + off; off += (size_t)NPTS * NPTS;
  int* knn = (int*)(ws + off); off += (size_t)NBATCH * NPTS * KNN;
  float* pmax = ws + off; off += (size_t)(NPTS / 128) * NBATCH * 1024;
  float* psum = ws + off; off += (size_t)(NPTS / 128) * NBATCH * 1024;
  float* pooled = ws + off;

  k_transpose<<<(NBATCH * NPTS * 3 + 255) / 256, 256, 0, stream>>>(x, h0);

  // ---- edge conv 1 (C=3 -> O=64)
  for (int b = 0; b < NBATCH; b++) {
    k_dist<3><<<dim3(NPTS / 64, NPTS / 64), 256, 0, stream>>>(h0 + (size_t)b * NPTS * 3, dist);
    k_topk<<<NPTS, 256, 0, stream>>>(dist, knn + (size_t)b * NPTS * KNN);
  }
  k_edge<3, 64><<<NBATCH * NPTS / 4, 256, 0, stream>>>(h0, knn, w1, g1, b1, x1);

  // ---- edge conv 2 (C=64 -> O=64)
  for (int b = 0; b < NBATCH; b++) {
    k_dist<64><<<dim3(NPTS / 64, NPTS / 64), 256, 0, stream>>>(x1 + (size_t)b * NPTS * 64, dist);
    k_topk<<<NPTS, 256, 0, stream>>>(dist, knn + (size_t)b * NPTS * KNN);
  }
  k_edge<64, 64><<<NBATCH * NPTS / 4, 256, 0, stream>>>(x1, knn, w2, g2, b2, x2);

  // ---- edge conv 3 (C=64 -> O=128)
  for (int b = 0; b < NBATCH; b++) {
    k_dist<64><<<dim3(NPTS / 64, NPTS / 64), 256, 0, stream>>>(x2 + (size_t)b * NPTS * 64, dist);
    k_topk<<<NPTS, 256, 0, stream>>>(dist, knn + (size_t)b * NPTS * KNN);
  }
  k_edge<64, 128><<<NBATCH * NPTS / 4, 256, 0, stream>>>(x2, knn, w3, g3, b3, x3);

  // ---- edge conv 4 (C=128 -> O=256)
  for (int b = 0; b < NBATCH; b++) {
    k_dist<128><<<dim3(NPTS / 64, NPTS / 64), 256, 0, stream>>>(x3 + (size_t)b * NPTS * 128, dist);
    k_topk<<<NPTS, 256, 0, stream>>>(dist, knn + (size_t)b * NPTS * KNN);
  }
  k_edge<128, 256><<<NBATCH * NPTS / 4, 256, 0, stream>>>(x3, knn, w4, g4, b4, x4);

  // ---- point MLP (tiled GEMM) + pooling + head
  k_mlp5<<<dim3(NBATCH * NPTS / 128, 8), 256, 0, stream>>>(x1, x2, x3, x4, w5, g5, b5,
                                                           pmax, psum);
  k_pool<<<(NBATCH * 1024 + 255) / 256, 256, 0, stream>>>(pmax, psum, pooled);
  k_head<<<NBATCH, 256, 0, stream>>>(pooled, wl1, g6, b6, wl2, bl2, g7, b7, wl3, bl3,
                                     (float*)d_out);
}

// Round 4
// 2327.107 us; speedup vs baseline: 1.3659x; 1.2732x over previous
//
#include <hip/hip_runtime.h>
#include <cstddef>
#include <cstdint>

#define NBATCH 8
#define NPTS   2048
#define KNN    20

// ---------------------------------------------------------------------------
// transpose (B,3,N) -> (B,N,3)
// ---------------------------------------------------------------------------
__global__ void k_transpose(const float* __restrict__ x, float* __restrict__ h0) {
  int i = blockIdx.x * 256 + threadIdx.x;
  if (i >= NBATCH * NPTS * 3) return;
  int c = i % 3;
  int n = (i / 3) % NPTS;
  int b = i / (3 * NPTS);
  h0[i] = x[((size_t)b * 3 + c) * NPTS + n];
}

// ---------------------------------------------------------------------------
// pairwise "distance" pd = 2*dot - sq_n - sq_m. blockIdx.z = batch within
// group; xg points at the group's first batch, dist has one NPTS*NPTS slab
// per z. grid (N/64, N/64, nb_grp), block 256, 4x4 microtile per thread.
// ---------------------------------------------------------------------------
template <int C>
__global__ __launch_bounds__(256) void k_dist(const float* __restrict__ xg,
                                              float* __restrict__ dist) {
  constexpr int PAD = (C % 4 == 0) ? 4 : 1;
  constexpr int S = C + PAD;
  __shared__ __attribute__((aligned(16))) float rows[64 * S];
  __shared__ __attribute__((aligned(16))) float cols[64 * S];
  __shared__ float sq[128];

  const float* xb = xg + (size_t)blockIdx.z * NPTS * C;
  float* db = dist + (size_t)blockIdx.z * NPTS * NPTS;
  const int rt = blockIdx.y, ct = blockIdx.x;
  const int tid = threadIdx.x;

  for (int e = tid; e < 64 * C; e += 256) {
    int i = e / C, c = e - i * C;
    rows[i * S + c] = xb[(size_t)(rt * 64 + i) * C + c];
    cols[i * S + c] = xb[(size_t)(ct * 64 + i) * C + c];
  }
  __syncthreads();
  if (tid < 128) {
    const float* p = (tid < 64) ? (rows + tid * S) : (cols + (tid - 64) * S);
    float s = 0.f;
    for (int c = 0; c < C; c++) s += p[c] * p[c];
    sq[tid] = s;
  }
  __syncthreads();

  const int r0 = (tid >> 4) * 4;
  const int c0 = (tid & 15) * 4;
  float acc[4][4] = {};

  if constexpr (C % 4 == 0) {
    for (int c = 0; c < C; c += 4) {
      float4 ra[4], cb[4];
#pragma unroll
      for (int i = 0; i < 4; i++) ra[i] = *(const float4*)&rows[(r0 + i) * S + c];
#pragma unroll
      for (int j = 0; j < 4; j++) cb[j] = *(const float4*)&cols[(c0 + j) * S + c];
#pragma unroll
      for (int i = 0; i < 4; i++)
#pragma unroll
        for (int j = 0; j < 4; j++)
          acc[i][j] += ra[i].x * cb[j].x + ra[i].y * cb[j].y +
                       ra[i].z * cb[j].z + ra[i].w * cb[j].w;
    }
  } else {
    for (int c = 0; c < C; c++) {
      float ra[4], cb[4];
#pragma unroll
      for (int i = 0; i < 4; i++) ra[i] = rows[(r0 + i) * S + c];
#pragma unroll
      for (int j = 0; j < 4; j++) cb[j] = cols[(c0 + j) * S + c];
#pragma unroll
      for (int i = 0; i < 4; i++)
#pragma unroll
        for (int j = 0; j < 4; j++) acc[i][j] += ra[i] * cb[j];
    }
  }

#pragma unroll
  for (int i = 0; i < 4; i++) {
    float sr = sq[r0 + i];
    float4 v;
    v.x = 2.f * acc[i][0] - sr - sq[64 + c0 + 0];
    v.y = 2.f * acc[i][1] - sr - sq[64 + c0 + 1];
    v.z = 2.f * acc[i][2] - sr - sq[64 + c0 + 2];
    v.w = 2.f * acc[i][3] - sr - sq[64 + c0 + 3];
    *(float4*)&db[(size_t)(rt * 64 + r0 + i) * NPTS + ct * 64 + c0] = v;
  }
}

// ---------------------------------------------------------------------------
// top-20 per row. grid (NPTS, nb_grp). Phase 1: per-wave shuffle-only top-20
// of its 512 elements. Phase 2: thread 0 4-way merge. Tie-break: lowest index.
// ---------------------------------------------------------------------------
__global__ __launch_bounds__(256) void k_topk(const float* __restrict__ dist,
                                              int* __restrict__ idx_out) {
  const int n = blockIdx.x;
  const int z = blockIdx.y;
  const float* drow = dist + ((size_t)z * NPTS + n) * NPTS;
  int* row_out = idx_out + ((size_t)z * NPTS + n) * KNN;
  const int tid = threadIdx.x;
  const int lane = tid & 63;
  const int wid = tid >> 6;
  __shared__ float cv[4][KNN];
  __shared__ int ci[4][KNN];

  float v[8];
#pragma unroll
  for (int i = 0; i < 8; i++) v[i] = drow[tid + i * 256];

  for (int k = 0; k < KNN; k++) {
    float bv = v[0];
    int bl = 0;
#pragma unroll
    for (int i = 1; i < 8; i++)
      if (v[i] > bv) { bv = v[i]; bl = i; }   // ascending i keeps lowest index
    int bi = bl * 256 + tid;
#pragma unroll
    for (int off = 32; off > 0; off >>= 1) {
      float ov = __shfl_down(bv, off);
      int oi = __shfl_down(bi, off);
      if (ov > bv || (ov == bv && oi < bi)) { bv = ov; bi = oi; }
    }
    bv = __shfl(bv, 0);
    bi = __shfl(bi, 0);
    if (lane == 0) { cv[wid][k] = bv; ci[wid][k] = bi; }
    if ((bi & 255) == tid) v[bi >> 8] = -3.0e38f;  // owner invalidates
  }
  __syncthreads();

  if (tid == 0) {
    int ptr[4] = {0, 0, 0, 0};
    for (int k = 0; k < KNN; k++) {
      float bb = -3.4e38f;
      int bi = 0x7fffffff, bw = 0;
#pragma unroll
      for (int w = 0; w < 4; w++) {
        if (ptr[w] < KNN) {
          float vv = cv[w][ptr[w]];
          int ii = ci[w][ptr[w]];
          if (vv > bb || (vv == bb && ii < bi)) { bb = vv; bi = ii; bw = w; }
        }
      }
      row_out[k] = bi;
      ptr[bw]++;
    }
  }
}

// ---------------------------------------------------------------------------
// edge conv: out[b,n,o] = max_k leaky((feat@w)*g + b), feat=[nb-ctr, ctr].
// Wave per point (4/block), thread computes JO=O/64 channels.
// Staging: raw neighbor rows only (k-loop, wave-uniform index, vector copy);
// center folded into t0 via ctr . (w_hi - w_lo).
// ---------------------------------------------------------------------------
template <int C, int O>
__global__ __launch_bounds__(256) void k_edge(const float* __restrict__ x,
                                              const int* __restrict__ knn,
                                              const float* __restrict__ w,
                                              const float* __restrict__ g,
                                              const float* __restrict__ bta,
                                              float* __restrict__ out) {
  constexpr int JO = O / 64;
  constexpr int NPB = 4;
  __shared__ __attribute__((aligned(16))) float nbd[NPB * KNN * C];
  __shared__ __attribute__((aligned(16))) float ctr[NPB * C];

  const int blk = blockIdx.x;
  const int b = blk / (NPTS / NPB);
  const int n0 = (blk % (NPTS / NPB)) * NPB;
  const int tid = threadIdx.x;
  const int lane = tid & 63;
  const int p = tid >> 6;
  const float* xb = x + (size_t)b * NPTS * C;

  for (int e = tid; e < NPB * C; e += 256) {
    int pp = e / C, c = e - pp * C;
    ctr[e] = xb[(size_t)(n0 + pp) * C + c];
  }
  // stage raw neighbor rows: wave per point, one k at a time
  {
    const int kbase = (b * NPTS + n0 + p) * KNN;
    float* nb_p = nbd + p * KNN * C;
#pragma unroll 4
    for (int k = 0; k < KNN; k++) {
      int m = knn[kbase + k];  // wave-uniform -> scalar load
      if constexpr (C == 128) {
        float2 vv = *(const float2*)&xb[(size_t)m * C + lane * 2];
        *(float2*)&nb_p[k * C + lane * 2] = vv;
      } else if constexpr (C == 64) {
        nb_p[k * C + lane] = xb[(size_t)m * C + lane];
      } else {
        if (lane < C) nb_p[k * C + lane] = xb[(size_t)m * C + lane];
      }
    }
  }
  __syncthreads();

  float acc[KNN][JO];
  {
    float t0[JO] = {};
    for (int c = 0; c < C; c++) {
      float cvv = ctr[p * C + c];
#pragma unroll
      for (int j = 0; j < JO; j++)
        t0[j] += cvv * (w[(size_t)(C + c) * O + j * 64 + lane] -
                        w[(size_t)c * O + j * 64 + lane]);
    }
#pragma unroll
    for (int k = 0; k < KNN; k++)
#pragma unroll
      for (int j = 0; j < JO; j++) acc[k][j] = t0[j];
  }

  const float* nb_p = nbd + p * KNN * C;
  if constexpr (C % 4 == 0) {
    for (int c = 0; c < C; c += 4) {
      float wv[4][JO];
#pragma unroll
      for (int cc = 0; cc < 4; cc++)
#pragma unroll
        for (int j = 0; j < JO; j++)
          wv[cc][j] = w[(size_t)(c + cc) * O + j * 64 + lane];
#pragma unroll
      for (int k = 0; k < KNN; k++) {
        float4 f = *(const float4*)&nb_p[k * C + c];
#pragma unroll
        for (int j = 0; j < JO; j++)
          acc[k][j] += f.x * wv[0][j] + f.y * wv[1][j] + f.z * wv[2][j] + f.w * wv[3][j];
      }
    }
  } else {
    for (int c = 0; c < C; c++) {
      float wv[JO];
#pragma unroll
      for (int j = 0; j < JO; j++) wv[j] = w[(size_t)c * O + j * 64 + lane];
#pragma unroll
      for (int k = 0; k < KNN; k++) {
        float f = nb_p[k * C + c];
#pragma unroll
        for (int j = 0; j < JO; j++) acc[k][j] += f * wv[j];
      }
    }
  }

#pragma unroll
  for (int j = 0; j < JO; j++) {
    const float gv = g[j * 64 + lane], bv = bta[j * 64 + lane];
    float mx = -3.0e38f;
#pragma unroll
    for (int k = 0; k < KNN; k++) {
      float h = acc[k][j] * gv + bv;
      h = (h >= 0.f) ? h : 0.2f * h;
      mx = fmaxf(mx, h);
    }
    out[(size_t)(b * NPTS + n0 + p) * O + j * 64 + lane] = mx;
  }
}

// ---------------------------------------------------------------------------
// point MLP 512->1024 as tiled fp32 GEMM. M=16384 pts, N=1024, K=512.
// 128x128 tile per block (256 thr, 8x8 microtile), K-tile 16.
// Epilogue: affine + leaky + max/sum pool over the 128-pt tile.
// ---------------------------------------------------------------------------
__global__ __launch_bounds__(256) void k_mlp5(const float* __restrict__ x1,
                                              const float* __restrict__ x2,
                                              const float* __restrict__ x3,
                                              const float* __restrict__ x4,
                                              const float* __restrict__ w5,
                                              const float* __restrict__ g5,
                                              const float* __restrict__ b5,
                                              float* __restrict__ pmax,
                                              float* __restrict__ psum) {
  constexpr int TM = 128, TN = 128, TK = 16, PAD = 4;
  __shared__ __attribute__((aligned(16))) float As[TK][TM + PAD];
  __shared__ __attribute__((aligned(16))) float Bs[TK][TN + PAD];

  const int mt = blockIdx.x;
  const int nt = blockIdx.y;
  const int tid = threadIdx.x;
  const int tx = tid & 15, ty = tid >> 4;
  const size_t m0 = (size_t)mt * TM;
  const int n0 = nt * TN;

  float acc[8][8] = {};

  for (int kt = 0; kt < 512; kt += TK) {
    const float* src;
    int cs, cw;
    if (kt < 64)       { src = x1; cs = kt;       cw = 64;  }
    else if (kt < 128) { src = x2; cs = kt - 64;  cw = 64;  }
    else if (kt < 256) { src = x3; cs = kt - 128; cw = 128; }
    else               { src = x4; cs = kt - 256; cw = 256; }
#pragma unroll
    for (int e = 0; e < 8; e++) {
      int idx = tid + e * 256;
      int m = idx >> 4, k = idx & 15;
      As[k][m] = src[(m0 + m) * cw + cs + k];
    }
#pragma unroll
    for (int e = 0; e < 8; e++) {
      int idx = tid + e * 256;
      int k = idx >> 7, nn = idx & 127;
      Bs[k][nn] = w5[(size_t)(kt + k) * 1024 + n0 + nn];
    }
    __syncthreads();
#pragma unroll
    for (int kk = 0; kk < TK; kk++) {
      float4 a0 = *(const float4*)&As[kk][ty * 8];
      float4 a1 = *(const float4*)&As[kk][ty * 8 + 4];
      float4 c0 = *(const float4*)&Bs[kk][tx * 8];
      float4 c1 = *(const float4*)&Bs[kk][tx * 8 + 4];
      float av[8] = {a0.x, a0.y, a0.z, a0.w, a1.x, a1.y, a1.z, a1.w};
      float bb[8] = {c0.x, c0.y, c0.z, c0.w, c1.x, c1.y, c1.z, c1.w};
#pragma unroll
      for (int i = 0; i < 8; i++)
#pragma unroll
        for (int j = 0; j < 8; j++) acc[i][j] += av[i] * bb[j];
    }
    __syncthreads();
  }

  float gv[8], bv[8], mx[8], sm[8];
#pragma unroll
  for (int j = 0; j < 8; j++) {
    gv[j] = g5[n0 + tx * 8 + j];
    bv[j] = b5[n0 + tx * 8 + j];
    mx[j] = -3.0e38f;
    sm[j] = 0.f;
  }
#pragma unroll
  for (int i = 0; i < 8; i++)
#pragma unroll
    for (int j = 0; j < 8; j++) {
      float h = acc[i][j] * gv[j] + bv[j];
      h = (h >= 0.f) ? h : 0.2f * h;
      mx[j] = fmaxf(mx[j], h);
      sm[j] += h;
    }

#pragma unroll
  for (int j = 0; j < 8; j++) {
    As[ty][tx * 8 + j] = mx[j];
    Bs[ty][tx * 8 + j] = sm[j];
  }
  __syncthreads();
  for (int s = 8; s > 0; s >>= 1) {
    if (ty < s) {
#pragma unroll
      for (int j = 0; j < 8; j++) {
        As[ty][tx * 8 + j] = fmaxf(As[ty][tx * 8 + j], As[ty + s][tx * 8 + j]);
        Bs[ty][tx * 8 + j] += Bs[ty + s][tx * 8 + j];
      }
    }
    __syncthreads();
  }
  if (ty == 0) {
#pragma unroll
    for (int j = 0; j < 8; j++) {
      pmax[(size_t)mt * 1024 + n0 + tx * 8 + j] = As[0][tx * 8 + j];
      psum[(size_t)mt * 1024 + n0 + tx * 8 + j] = Bs[0][tx * 8 + j];
    }
  }
}

// ---------------------------------------------------------------------------
// reduce tile partials -> pooled (B, 2048) = [max(1024), mean(1024)]
// ---------------------------------------------------------------------------
__global__ void k_pool(const float* __restrict__ pmax, const float* __restrict__ psum,
                       float* __restrict__ pooled) {
  int i = blockIdx.x * 256 + threadIdx.x;
  if (i >= NBATCH * 1024) return;
  int b = i / 1024, e = i - b * 1024;
  constexpr int NT = NPTS / 128;
  float mx = -3.0e38f, sm = 0.f;
  for (int t = 0; t < NT; t++) {
    mx = fmaxf(mx, pmax[((size_t)b * NT + t) * 1024 + e]);
    sm += psum[((size_t)b * NT + t) * 1024 + e];
  }
  pooled[(size_t)b * 2048 + e] = mx;
  pooled[(size_t)b * 2048 + 1024 + e] = sm * (1.0f / NPTS);
}

// ---------------------------------------------------------------------------
// FC head: 2048->512 (leaky, affine) -> 256 (bias, leaky, affine) -> 40 (+bias)
// ---------------------------------------------------------------------------
__global__ __launch_bounds__(256) void k_head(const float* __restrict__ pooled,
                                              const float* __restrict__ wl1,
                                              const float* __restrict__ g6,
                                              const float* __restrict__ b6,
                                              const float* __restrict__ wl2,
                                              const float* __restrict__ bl2,
                                              const float* __restrict__ g7,
                                              const float* __restrict__ b7,
                                              const float* __restrict__ wl3,
                                              const float* __restrict__ bl3,
                                              float* __restrict__ out) {
  const int b = blockIdx.x;
  const int tid = threadIdx.x;
  __shared__ float pl[2048];
  __shared__ float h1[512];
  __shared__ float h2[256];

  for (int i = tid; i < 2048; i += 256) pl[i] = pooled[(size_t)b * 2048 + i];
  __syncthreads();

  for (int o = tid; o < 512; o += 256) {
    float a = 0.f;
    for (int c = 0; c < 2048; c++) a += pl[c] * wl1[(size_t)c * 512 + o];
    a = a * g6[o] + b6[o];
    h1[o] = (a >= 0.f) ? a : 0.2f * a;
  }
  __syncthreads();

  {
    float a = 0.f;
    for (int c = 0; c < 512; c++) a += h1[c] * wl2[(size_t)c * 256 + tid];
    a = (a + bl2[tid]) * g7[tid] + b7[tid];
    h2[tid] = (a >= 0.f) ? a : 0.2f * a;
  }
  __syncthreads();

  if (tid < 40) {
    float a = bl3[tid];
    for (int c = 0; c < 256; c++) a += h2[c] * wl3[(size_t)c * 40 + tid];
    out[(size_t)b * 40 + tid] = a;
  }
}

// ---------------------------------------------------------------------------
extern "C" void kernel_launch(void* const* d_in, const int* in_sizes, int n_in,
                              void* d_out, int out_size, void* d_ws, size_t ws_size,
                              hipStream_t stream) {
  (void)in_sizes; (void)n_in; (void)out_size;
  const float* x   = (const float*)d_in[0];
  const float* w1  = (const float*)d_in[1];
  const float* g1  = (const float*)d_in[2];
  const float* b1  = (const float*)d_in[3];
  const float* w2  = (const float*)d_in[4];
  const float* g2  = (const float*)d_in[5];
  const float* b2  = (const float*)d_in[6];
  const float* w3  = (const float*)d_in[7];
  const float* g3  = (const float*)d_in[8];
  const float* b3  = (const float*)d_in[9];
  const float* w4  = (const float*)d_in[10];
  const float* g4  = (const float*)d_in[11];
  const float* b4  = (const float*)d_in[12];
  const float* w5  = (const float*)d_in[13];
  const float* g5  = (const float*)d_in[14];
  const float* b5  = (const float*)d_in[15];
  const float* wl1 = (const float*)d_in[16];
  const float* g6  = (const float*)d_in[17];
  const float* b6  = (const float*)d_in[18];
  const float* wl2 = (const float*)d_in[19];
  const float* bl2 = (const float*)d_in[20];
  const float* g7  = (const float*)d_in[21];
  const float* b7  = (const float*)d_in[22];
  const float* wl3 = (const float*)d_in[23];
  const float* bl3 = (const float*)d_in[24];

  float* ws = (float*)d_ws;
  size_t off = 0;
  float* h0 = ws + off;   off += (size_t)NBATCH * NPTS * 3;
  float* x1 = ws + off;   off += (size_t)NBATCH * NPTS * 64;
  float* x2 = ws + off;   off += (size_t)NBATCH * NPTS * 64;
  float* x3 = ws + off;   off += (size_t)NBATCH * NPTS * 128;
  float* x4 = ws + off;   off += (size_t)NBATCH * NPTS * 256;
  int* knn = (int*)(ws + off); off += (size_t)NBATCH * NPTS * KNN;
  float* pmax = ws + off; off += (size_t)(NPTS / 128) * NBATCH * 1024;
  float* psum = ws + off; off += (size_t)(NPTS / 128) * NBATCH * 1024;
  float* pooled = ws + off; off += (size_t)NBATCH * 2048;
  float* dist = ws + off;  // adaptive: nb_grp * NPTS * NPTS floats, placed last

  // pick the largest batch-group whose dist slabs fit in the remaining ws.
  // ws_size is constant across calls -> identical work every call (graph-safe).
  size_t avail = ws_size / 4 - off;
  int nb_grp = 8;
  while (nb_grp > 1 && (size_t)nb_grp * NPTS * NPTS > avail) nb_grp >>= 1;

  k_transpose<<<(NBATCH * NPTS * 3 + 255) / 256, 256, 0, stream>>>(x, h0);

  // ---- edge conv 1 (C=3 -> O=64)
  for (int b0 = 0; b0 < NBATCH; b0 += nb_grp) {
    k_dist<3><<<dim3(NPTS / 64, NPTS / 64, nb_grp), 256, 0, stream>>>(
        h0 + (size_t)b0 * NPTS * 3, dist);
    k_topk<<<dim3(NPTS, nb_grp), 256, 0, stream>>>(dist, knn + (size_t)b0 * NPTS * KNN);
  }
  k_edge<3, 64><<<NBATCH * NPTS / 4, 256, 0, stream>>>(h0, knn, w1, g1, b1, x1);

  // ---- edge conv 2 (C=64 -> O=64)
  for (int b0 = 0; b0 < NBATCH; b0 += nb_grp) {
    k_dist<64><<<dim3(NPTS / 64, NPTS / 64, nb_grp), 256, 0, stream>>>(
        x1 + (size_t)b0 * NPTS * 64, dist);
    k_topk<<<dim3(NPTS, nb_grp), 256, 0, stream>>>(dist, knn + (size_t)b0 * NPTS * KNN);
  }
  k_edge<64, 64><<<NBATCH * NPTS / 4, 256, 0, stream>>>(x1, knn, w2, g2, b2, x2);

  // ---- edge conv 3 (C=64 -> O=128)
  for (int b0 = 0; b0 < NBATCH; b0 += nb_grp) {
    k_dist<64><<<dim3(NPTS / 64, NPTS / 64, nb_grp), 256, 0, stream>>>(
        x2 + (size_t)b0 * NPTS * 64, dist);
    k_topk<<<dim3(NPTS, nb_grp), 256, 0, stream>>>(dist, knn + (size_t)b0 * NPTS * KNN);
  }
  k_edge<64, 128><<<NBATCH * NPTS / 4, 256, 0, stream>>>(x2, knn, w3, g3, b3, x3);

  // ---- edge conv 4 (C=128 -> O=256)
  for (int b0 = 0; b0 < NBATCH; b0 += nb_grp) {
    k_dist<128><<<dim3(NPTS / 64, NPTS / 64, nb_grp), 256, 0, stream>>>(
        x3 + (size_t)b0 * NPTS * 128, dist);
    k_topk<<<dim3(NPTS, nb_grp), 256, 0, stream>>>(dist, knn + (size_t)b0 * NPTS * KNN);
  }
  k_edge<128, 256><<<NBATCH * NPTS / 4, 256, 0, stream>>>(x3, knn, w4, g4, b4, x4);

  // ---- point MLP (tiled GEMM) + pooling + head
  k_mlp5<<<dim3(NBATCH * NPTS / 128, 8), 256, 0, stream>>>(x1, x2, x3, x4, w5, g5, b5,
                                                           pmax, psum);
  k_pool<<<(NBATCH * 1024 + 255) / 256, 256, 0, stream>>>(pmax, psum, pooled);
  k_head<<<NBATCH, 256, 0, stream>>>(pooled, wl1, g6, b6, wl2, bl2, g7, b7, wl3, bl3,
                                     (float*)d_out);
}

// Round 5
// 2237.218 us; speedup vs baseline: 1.4208x; 1.0402x over previous
//
#include <hip/hip_runtime.h>
#include <cstddef>
#include <cstdint>

#define NBATCH 8
#define NPTS   2048
#define KNN    20

// ---------------------------------------------------------------------------
// transpose (B,3,N) -> (B,N,3)
// ---------------------------------------------------------------------------
__global__ void k_transpose(const float* __restrict__ x, float* __restrict__ h0) {
  int i = blockIdx.x * 256 + threadIdx.x;
  if (i >= NBATCH * NPTS * 3) return;
  int c = i % 3;
  int n = (i / 3) % NPTS;
  int b = i / (3 * NPTS);
  h0[i] = x[((size_t)b * 3 + c) * NPTS + n];
}

// ---------------------------------------------------------------------------
// pairwise "distance" pd = 2*dot - sq_n - sq_m. blockIdx.z = batch in group.
// ---------------------------------------------------------------------------
template <int C>
__global__ __launch_bounds__(256) void k_dist(const float* __restrict__ xg,
                                              float* __restrict__ dist) {
  constexpr int PAD = (C % 4 == 0) ? 4 : 1;
  constexpr int S = C + PAD;
  __shared__ __attribute__((aligned(16))) float rows[64 * S];
  __shared__ __attribute__((aligned(16))) float cols[64 * S];
  __shared__ float sq[128];

  const float* xb = xg + (size_t)blockIdx.z * NPTS * C;
  float* db = dist + (size_t)blockIdx.z * NPTS * NPTS;
  const int rt = blockIdx.y, ct = blockIdx.x;
  const int tid = threadIdx.x;

  for (int e = tid; e < 64 * C; e += 256) {
    int i = e / C, c = e - i * C;
    rows[i * S + c] = xb[(size_t)(rt * 64 + i) * C + c];
    cols[i * S + c] = xb[(size_t)(ct * 64 + i) * C + c];
  }
  __syncthreads();
  if (tid < 128) {
    const float* p = (tid < 64) ? (rows + tid * S) : (cols + (tid - 64) * S);
    float s = 0.f;
    for (int c = 0; c < C; c++) s += p[c] * p[c];
    sq[tid] = s;
  }
  __syncthreads();

  const int r0 = (tid >> 4) * 4;
  const int c0 = (tid & 15) * 4;
  float acc[4][4] = {};

  if constexpr (C % 4 == 0) {
    for (int c = 0; c < C; c += 4) {
      float4 ra[4], cb[4];
#pragma unroll
      for (int i = 0; i < 4; i++) ra[i] = *(const float4*)&rows[(r0 + i) * S + c];
#pragma unroll
      for (int j = 0; j < 4; j++) cb[j] = *(const float4*)&cols[(c0 + j) * S + c];
#pragma unroll
      for (int i = 0; i < 4; i++)
#pragma unroll
        for (int j = 0; j < 4; j++)
          acc[i][j] += ra[i].x * cb[j].x + ra[i].y * cb[j].y +
                       ra[i].z * cb[j].z + ra[i].w * cb[j].w;
    }
  } else {
    for (int c = 0; c < C; c++) {
      float ra[4], cb[4];
#pragma unroll
      for (int i = 0; i < 4; i++) ra[i] = rows[(r0 + i) * S + c];
#pragma unroll
      for (int j = 0; j < 4; j++) cb[j] = cols[(c0 + j) * S + c];
#pragma unroll
      for (int i = 0; i < 4; i++)
#pragma unroll
        for (int j = 0; j < 4; j++) acc[i][j] += ra[i] * cb[j];
    }
  }

#pragma unroll
  for (int i = 0; i < 4; i++) {
    float sr = sq[r0 + i];
    float4 v;
    v.x = 2.f * acc[i][0] - sr - sq[64 + c0 + 0];
    v.y = 2.f * acc[i][1] - sr - sq[64 + c0 + 1];
    v.z = 2.f * acc[i][2] - sr - sq[64 + c0 + 2];
    v.w = 2.f * acc[i][3] - sr - sq[64 + c0 + 3];
    *(float4*)&db[(size_t)(rt * 64 + r0 + i) * NPTS + ct * 64 + c0] = v;
  }
}

// ---------------------------------------------------------------------------
// top-20 per row. grid (NPTS, nb_grp). Per-wave shuffle top-20, then thread-0
// 4-way merge. NO dynamic register indexing (avoids scratch spill).
// ---------------------------------------------------------------------------
__global__ __launch_bounds__(256) void k_topk(const float* __restrict__ dist,
                                              int* __restrict__ idx_out) {
  const int n = blockIdx.x;
  const int z = blockIdx.y;
  const float* drow = dist + ((size_t)z * NPTS + n) * NPTS;
  int* row_out = idx_out + ((size_t)z * NPTS + n) * KNN;
  const int tid = threadIdx.x;
  const int lane = tid & 63;
  const int wid = tid >> 6;
  __shared__ float cv[4][KNN];
  __shared__ int ci[4][KNN];

  float v[8];
#pragma unroll
  for (int i = 0; i < 8; i++) v[i] = drow[tid + i * 256];

  for (int k = 0; k < KNN; k++) {
    float bv = v[0];
    int bl = 0;
#pragma unroll
    for (int i = 1; i < 8; i++)
      if (v[i] > bv) { bv = v[i]; bl = i; }   // ascending i keeps lowest index
    int bi = bl * 256 + tid;
#pragma unroll
    for (int off = 32; off > 0; off >>= 1) {
      float ov = __shfl_down(bv, off);
      int oi = __shfl_down(bi, off);
      if (ov > bv || (ov == bv && oi < bi)) { bv = ov; bi = oi; }
    }
    bv = __shfl(bv, 0);
    bi = __shfl(bi, 0);
    if (lane == 0) { cv[wid][k] = bv; ci[wid][k] = bi; }
    // owner invalidates -- static indices only (no scratch spill)
    int slot = ((bi & 255) == tid) ? (bi >> 8) : -1;
#pragma unroll
    for (int i = 0; i < 8; i++)
      if (slot == i) v[i] = -3.0e38f;
  }
  __syncthreads();

  if (tid == 0) {
    int ptr[4] = {0, 0, 0, 0};
    for (int k = 0; k < KNN; k++) {
      float bb = -3.4e38f;
      int bi = 0x7fffffff, bw = 0;
#pragma unroll
      for (int w = 0; w < 4; w++) {
        if (ptr[w] < KNN) {
          float vv = cv[w][ptr[w]];
          int ii = ci[w][ptr[w]];
          if (vv > bb || (vv == bb && ii < bi)) { bb = vv; bi = ii; bw = w; }
        }
      }
      row_out[k] = bi;
      ptr[bw]++;
    }
  }
}

// ---------------------------------------------------------------------------
// t0 GEMM: t0buf[n, o] = sum_c x[n, c] * w[C+c, o]   (center @ w_hi)
// 128x64 tile, 256 threads, 8x4 microtile, TK=16. C must be mult of 16.
// ---------------------------------------------------------------------------
template <int C, int O>
__global__ __launch_bounds__(256) void k_t0(const float* __restrict__ x,
                                            const float* __restrict__ w,
                                            float* __restrict__ t0buf) {
  constexpr int TM = 128, TN = 64, TK = 16;
  __shared__ __attribute__((aligned(16))) float As[TK][TM + 4];
  __shared__ __attribute__((aligned(16))) float Bs[TK][TN + 4];
  const int mt = blockIdx.x, nt = blockIdx.y;
  const int tid = threadIdx.x;
  const int tx = tid & 15, ty = tid >> 4;
  const size_t m0 = (size_t)mt * TM;
  const int n0 = nt * TN;
  float acc[8][4] = {};

  for (int kt = 0; kt < C; kt += TK) {
#pragma unroll
    for (int e = 0; e < 8; e++) {
      int idx = tid + e * 256;
      int m = idx >> 4, k = idx & 15;
      As[k][m] = x[(m0 + m) * C + kt + k];
    }
#pragma unroll
    for (int e = 0; e < 4; e++) {
      int idx = tid + e * 256;
      int k = idx >> 6, nn = idx & 63;
      Bs[k][nn] = w[(size_t)(C + kt + k) * O + n0 + nn];
    }
    __syncthreads();
#pragma unroll
    for (int kk = 0; kk < TK; kk++) {
      float4 a0 = *(const float4*)&As[kk][ty * 8];
      float4 a1 = *(const float4*)&As[kk][ty * 8 + 4];
      float4 b0 = *(const float4*)&Bs[kk][tx * 4];
      float av[8] = {a0.x, a0.y, a0.z, a0.w, a1.x, a1.y, a1.z, a1.w};
      float bb[4] = {b0.x, b0.y, b0.z, b0.w};
#pragma unroll
      for (int i = 0; i < 8; i++)
#pragma unroll
        for (int j = 0; j < 4; j++) acc[i][j] += av[i] * bb[j];
    }
    __syncthreads();
  }
#pragma unroll
  for (int i = 0; i < 8; i++)
#pragma unroll
    for (int j = 0; j < 4; j++)
      t0buf[(m0 + ty * 8 + i) * O + n0 + tx * 4 + j] = acc[i][j];
}

// ---------------------------------------------------------------------------
// edge conv: out[b,n,o] = max_k leaky((feat@w)*g + b), feat=[nb-ctr, ctr]
//          = max_k leaky((((nb-ctr)@w_lo) + t0)*g + b),  t0 = ctr@w_hi.
// Wave per point (4/block). Staging is wave-private (no __syncthreads):
// lane owns fixed channels, subtracts its center register, 20 loads in flight.
// ---------------------------------------------------------------------------
template <int C, int O, bool USE_T0>
__global__ __launch_bounds__(256) void k_edge(const float* __restrict__ x,
                                              const int* __restrict__ knn,
                                              const float* __restrict__ w,
                                              const float* __restrict__ t0buf,
                                              const float* __restrict__ g,
                                              const float* __restrict__ bta,
                                              float* __restrict__ out) {
  constexpr int JO = O / 64;
  constexpr int NPB = 4;
  __shared__ __attribute__((aligned(16))) float nbd[NPB * KNN * C];

  const int blk = blockIdx.x;
  const int b = blk / (NPTS / NPB);
  const int n0 = (blk % (NPTS / NPB)) * NPB;
  const int tid = threadIdx.x;
  const int lane = tid & 63;
  const int p = tid >> 6;
  const float* xb = x + (size_t)b * NPTS * C;

  const int kbase = (b * NPTS + n0 + p) * KNN;
  float* nb_p = nbd + p * KNN * C;
  int midx[KNN];
#pragma unroll
  for (int k = 0; k < KNN; k++) midx[k] = knn[kbase + k];

  float cv0 = 0.f, cv1 = 0.f;
  if constexpr (C == 128) {
    float2 cc = *(const float2*)&xb[(size_t)(n0 + p) * C + lane * 2];
    cv0 = cc.x; cv1 = cc.y;
    float2 vv[KNN];
#pragma unroll
    for (int k = 0; k < KNN; k++)
      vv[k] = *(const float2*)&xb[(size_t)midx[k] * C + lane * 2];
#pragma unroll
    for (int k = 0; k < KNN; k++) {
      float2 d; d.x = vv[k].x - cv0; d.y = vv[k].y - cv1;
      *(float2*)&nb_p[k * C + lane * 2] = d;
    }
  } else if constexpr (C == 64) {
    cv0 = xb[(size_t)(n0 + p) * C + lane];
    float vv[KNN];
#pragma unroll
    for (int k = 0; k < KNN; k++) vv[k] = xb[(size_t)midx[k] * C + lane];
#pragma unroll
    for (int k = 0; k < KNN; k++) nb_p[k * C + lane] = vv[k] - cv0;
  } else {  // C == 3
    if (lane < C) cv0 = xb[(size_t)(n0 + p) * C + lane];
    float vv[KNN];
#pragma unroll
    for (int k = 0; k < KNN; k++)
      vv[k] = (lane < C) ? xb[(size_t)midx[k] * C + lane] : 0.f;
#pragma unroll
    for (int k = 0; k < KNN; k++)
      if (lane < C) nb_p[k * C + lane] = vv[k] - cv0;
  }
  // NOTE: no __syncthreads -- each wave reads only the LDS rows it wrote.

  float acc[KNN][JO];
  {
    float t0[JO];
    if constexpr (USE_T0) {
#pragma unroll
      for (int j = 0; j < JO; j++)
        t0[j] = t0buf[(size_t)(b * NPTS + n0 + p) * O + j * 64 + lane];
    } else {
      // C==3: t0 = ctr @ w_hi via shuffle of the 3 center regs
#pragma unroll
      for (int j = 0; j < JO; j++) t0[j] = 0.f;
      for (int c = 0; c < C; c++) {
        float cc = __shfl(cv0, c);
#pragma unroll
        for (int j = 0; j < JO; j++)
          t0[j] += cc * w[(size_t)(C + c) * O + j * 64 + lane];
      }
    }
#pragma unroll
    for (int k = 0; k < KNN; k++)
#pragma unroll
      for (int j = 0; j < JO; j++) acc[k][j] = t0[j];
  }

  if constexpr (C % 4 == 0) {
    for (int c = 0; c < C; c += 4) {
      float wv[4][JO];
#pragma unroll
      for (int cc = 0; cc < 4; cc++)
#pragma unroll
        for (int j = 0; j < JO; j++)
          wv[cc][j] = w[(size_t)(c + cc) * O + j * 64 + lane];
#pragma unroll
      for (int k = 0; k < KNN; k++) {
        float4 f = *(const float4*)&nb_p[k * C + c];
#pragma unroll
        for (int j = 0; j < JO; j++)
          acc[k][j] += f.x * wv[0][j] + f.y * wv[1][j] + f.z * wv[2][j] + f.w * wv[3][j];
      }
    }
  } else {
    for (int c = 0; c < C; c++) {
      float wv[JO];
#pragma unroll
      for (int j = 0; j < JO; j++) wv[j] = w[(size_t)c * O + j * 64 + lane];
#pragma unroll
      for (int k = 0; k < KNN; k++) {
        float f = nb_p[k * C + c];
#pragma unroll
        for (int j = 0; j < JO; j++) acc[k][j] += f * wv[j];
      }
    }
  }

#pragma unroll
  for (int j = 0; j < JO; j++) {
    const float gv = g[j * 64 + lane], bv = bta[j * 64 + lane];
    float mx = -3.0e38f;
#pragma unroll
    for (int k = 0; k < KNN; k++) {
      float h = acc[k][j] * gv + bv;
      h = (h >= 0.f) ? h : 0.2f * h;
      mx = fmaxf(mx, h);
    }
    out[(size_t)(b * NPTS + n0 + p) * O + j * 64 + lane] = mx;
  }
}

// ---------------------------------------------------------------------------
// point MLP 512->1024 as tiled fp32 GEMM + fused affine/leaky/pool epilogue.
// ---------------------------------------------------------------------------
__global__ __launch_bounds__(256) void k_mlp5(const float* __restrict__ x1,
                                              const float* __restrict__ x2,
                                              const float* __restrict__ x3,
                                              const float* __restrict__ x4,
                                              const float* __restrict__ w5,
                                              const float* __restrict__ g5,
                                              const float* __restrict__ b5,
                                              float* __restrict__ pmax,
                                              float* __restrict__ psum) {
  constexpr int TM = 128, TN = 128, TK = 16, PAD = 4;
  __shared__ __attribute__((aligned(16))) float As[TK][TM + PAD];
  __shared__ __attribute__((aligned(16))) float Bs[TK][TN + PAD];

  const int mt = blockIdx.x;
  const int nt = blockIdx.y;
  const int tid = threadIdx.x;
  const int tx = tid & 15, ty = tid >> 4;
  const size_t m0 = (size_t)mt * TM;
  const int n0 = nt * TN;

  float acc[8][8] = {};

  for (int kt = 0; kt < 512; kt += TK) {
    const float* src;
    int cs, cw;
    if (kt < 64)       { src = x1; cs = kt;       cw = 64;  }
    else if (kt < 128) { src = x2; cs = kt - 64;  cw = 64;  }
    else if (kt < 256) { src = x3; cs = kt - 128; cw = 128; }
    else               { src = x4; cs = kt - 256; cw = 256; }
#pragma unroll
    for (int e = 0; e < 8; e++) {
      int idx = tid + e * 256;
      int m = idx >> 4, k = idx & 15;
      As[k][m] = src[(m0 + m) * cw + cs + k];
    }
#pragma unroll
    for (int e = 0; e < 8; e++) {
      int idx = tid + e * 256;
      int k = idx >> 7, nn = idx & 127;
      Bs[k][nn] = w5[(size_t)(kt + k) * 1024 + n0 + nn];
    }
    __syncthreads();
#pragma unroll
    for (int kk = 0; kk < TK; kk++) {
      float4 a0 = *(const float4*)&As[kk][ty * 8];
      float4 a1 = *(const float4*)&As[kk][ty * 8 + 4];
      float4 c0 = *(const float4*)&Bs[kk][tx * 8];
      float4 c1 = *(const float4*)&Bs[kk][tx * 8 + 4];
      float av[8] = {a0.x, a0.y, a0.z, a0.w, a1.x, a1.y, a1.z, a1.w};
      float bb[8] = {c0.x, c0.y, c0.z, c0.w, c1.x, c1.y, c1.z, c1.w};
#pragma unroll
      for (int i = 0; i < 8; i++)
#pragma unroll
        for (int j = 0; j < 8; j++) acc[i][j] += av[i] * bb[j];
    }
    __syncthreads();
  }

  float gv[8], bv[8], mx[8], sm[8];
#pragma unroll
  for (int j = 0; j < 8; j++) {
    gv[j] = g5[n0 + tx * 8 + j];
    bv[j] = b5[n0 + tx * 8 + j];
    mx[j] = -3.0e38f;
    sm[j] = 0.f;
  }
#pragma unroll
  for (int i = 0; i < 8; i++)
#pragma unroll
    for (int j = 0; j < 8; j++) {
      float h = acc[i][j] * gv[j] + bv[j];
      h = (h >= 0.f) ? h : 0.2f * h;
      mx[j] = fmaxf(mx[j], h);
      sm[j] += h;
    }

#pragma unroll
  for (int j = 0; j < 8; j++) {
    As[ty][tx * 8 + j] = mx[j];
    Bs[ty][tx * 8 + j] = sm[j];
  }
  __syncthreads();
  for (int s = 8; s > 0; s >>= 1) {
    if (ty < s) {
#pragma unroll
      for (int j = 0; j < 8; j++) {
        As[ty][tx * 8 + j] = fmaxf(As[ty][tx * 8 + j], As[ty + s][tx * 8 + j]);
        Bs[ty][tx * 8 + j] += Bs[ty + s][tx * 8 + j];
      }
    }
    __syncthreads();
  }
  if (ty == 0) {
#pragma unroll
    for (int j = 0; j < 8; j++) {
      pmax[(size_t)mt * 1024 + n0 + tx * 8 + j] = As[0][tx * 8 + j];
      psum[(size_t)mt * 1024 + n0 + tx * 8 + j] = Bs[0][tx * 8 + j];
    }
  }
}

// ---------------------------------------------------------------------------
// reduce tile partials -> pooled (B, 2048) = [max(1024), mean(1024)]
// ---------------------------------------------------------------------------
__global__ void k_pool(const float* __restrict__ pmax, const float* __restrict__ psum,
                       float* __restrict__ pooled) {
  int i = blockIdx.x * 256 + threadIdx.x;
  if (i >= NBATCH * 1024) return;
  int b = i / 1024, e = i - b * 1024;
  constexpr int NT = NPTS / 128;
  float mx = -3.0e38f, sm = 0.f;
  for (int t = 0; t < NT; t++) {
    mx = fmaxf(mx, pmax[((size_t)b * NT + t) * 1024 + e]);
    sm += psum[((size_t)b * NT + t) * 1024 + e];
  }
  pooled[(size_t)b * 2048 + e] = mx;
  pooled[(size_t)b * 2048 + 1024 + e] = sm * (1.0f / NPTS);
}

// ---------------------------------------------------------------------------
// FC head: 2048->512 (leaky, affine) -> 256 (bias, leaky, affine) -> 40 (+bias)
// ---------------------------------------------------------------------------
__global__ __launch_bounds__(256) void k_head(const float* __restrict__ pooled,
                                              const float* __restrict__ wl1,
                                              const float* __restrict__ g6,
                                              const float* __restrict__ b6,
                                              const float* __restrict__ wl2,
                                              const float* __restrict__ bl2,
                                              const float* __restrict__ g7,
                                              const float* __restrict__ b7,
                                              const float* __restrict__ wl3,
                                              const float* __restrict__ bl3,
                                              float* __restrict__ out) {
  const int b = blockIdx.x;
  const int tid = threadIdx.x;
  __shared__ float pl[2048];
  __shared__ float h1[512];
  __shared__ float h2[256];

  for (int i = tid; i < 2048; i += 256) pl[i] = pooled[(size_t)b * 2048 + i];
  __syncthreads();

  for (int o = tid; o < 512; o += 256) {
    float a = 0.f;
    for (int c = 0; c < 2048; c++) a += pl[c] * wl1[(size_t)c * 512 + o];
    a = a * g6[o] + b6[o];
    h1[o] = (a >= 0.f) ? a : 0.2f * a;
  }
  __syncthreads();

  {
    float a = 0.f;
    for (int c = 0; c < 512; c++) a += h1[c] * wl2[(size_t)c * 256 + tid];
    a = (a + bl2[tid]) * g7[tid] + b7[tid];
    h2[tid] = (a >= 0.f) ? a : 0.2f * a;
  }
  __syncthreads();

  if (tid < 40) {
    float a = bl3[tid];
    for (int c = 0; c < 256; c++) a += h2[c] * wl3[(size_t)c * 40 + tid];
    out[(size_t)b * 40 + tid] = a;
  }
}

// ---------------------------------------------------------------------------
extern "C" void kernel_launch(void* const* d_in, const int* in_sizes, int n_in,
                              void* d_out, int out_size, void* d_ws, size_t ws_size,
                              hipStream_t stream) {
  (void)in_sizes; (void)n_in; (void)out_size;
  const float* x   = (const float*)d_in[0];
  const float* w1  = (const float*)d_in[1];
  const float* g1  = (const float*)d_in[2];
  const float* b1  = (const float*)d_in[3];
  const float* w2  = (const float*)d_in[4];
  const float* g2  = (const float*)d_in[5];
  const float* b2  = (const float*)d_in[6];
  const float* w3  = (const float*)d_in[7];
  const float* g3  = (const float*)d_in[8];
  const float* b3  = (const float*)d_in[9];
  const float* w4  = (const float*)d_in[10];
  const float* g4  = (const float*)d_in[11];
  const float* b4  = (const float*)d_in[12];
  const float* w5  = (const float*)d_in[13];
  const float* g5  = (const float*)d_in[14];
  const float* b5  = (const float*)d_in[15];
  const float* wl1 = (const float*)d_in[16];
  const float* g6  = (const float*)d_in[17];
  const float* b6  = (const float*)d_in[18];
  const float* wl2 = (const float*)d_in[19];
  const float* bl2 = (const float*)d_in[20];
  const float* g7  = (const float*)d_in[21];
  const float* b7  = (const float*)d_in[22];
  const float* wl3 = (const float*)d_in[23];
  const float* bl3 = (const float*)d_in[24];

  float* ws = (float*)d_ws;
  size_t off = 0;
  float* h0 = ws + off;   off += (size_t)NBATCH * NPTS * 3;
  float* x1 = ws + off;   off += (size_t)NBATCH * NPTS * 64;
  float* x2 = ws + off;   off += (size_t)NBATCH * NPTS * 64;
  float* x3 = ws + off;   off += (size_t)NBATCH * NPTS * 128;
  float* x4 = ws + off;   off += (size_t)NBATCH * NPTS * 256;
  int* knn = (int*)(ws + off); off += (size_t)NBATCH * NPTS * KNN;
  float* pmax = ws + off; off += (size_t)(NPTS / 128) * NBATCH * 1024;
  float* psum = ws + off; off += (size_t)(NPTS / 128) * NBATCH * 1024;
  float* pooled = ws + off; off += (size_t)NBATCH * 2048;
  float* t0buf = ws + off;  off += (size_t)NBATCH * NPTS * 256;  // max O
  float* dist = ws + off;  // adaptive: nb_grp * NPTS * NPTS floats, placed last

  size_t avail = ws_size / 4 - off;
  int nb_grp = 8;
  while (nb_grp > 1 && (size_t)nb_grp * NPTS * NPTS > avail) nb_grp >>= 1;

  k_transpose<<<(NBATCH * NPTS * 3 + 255) / 256, 256, 0, stream>>>(x, h0);

  // ---- edge conv 1 (C=3 -> O=64)
  for (int b0 = 0; b0 < NBATCH; b0 += nb_grp) {
    k_dist<3><<<dim3(NPTS / 64, NPTS / 64, nb_grp), 256, 0, stream>>>(
        h0 + (size_t)b0 * NPTS * 3, dist);
    k_topk<<<dim3(NPTS, nb_grp), 256, 0, stream>>>(dist, knn + (size_t)b0 * NPTS * KNN);
  }
  k_edge<3, 64, false><<<NBATCH * NPTS / 4, 256, 0, stream>>>(h0, knn, w1, nullptr,
                                                              g1, b1, x1);

  // ---- edge conv 2 (C=64 -> O=64)
  for (int b0 = 0; b0 < NBATCH; b0 += nb_grp) {
    k_dist<64><<<dim3(NPTS / 64, NPTS / 64, nb_grp), 256, 0, stream>>>(
        x1 + (size_t)b0 * NPTS * 64, dist);
    k_topk<<<dim3(NPTS, nb_grp), 256, 0, stream>>>(dist, knn + (size_t)b0 * NPTS * KNN);
  }
  k_t0<64, 64><<<dim3(NBATCH * NPTS / 128, 1), 256, 0, stream>>>(x1, w2, t0buf);
  k_edge<64, 64, true><<<NBATCH * NPTS / 4, 256, 0, stream>>>(x1, knn, w2, t0buf,
                                                              g2, b2, x2);

  // ---- edge conv 3 (C=64 -> O=128)
  for (int b0 = 0; b0 < NBATCH; b0 += nb_grp) {
    k_dist<64><<<dim3(NPTS / 64, NPTS / 64, nb_grp), 256, 0, stream>>>(
        x2 + (size_t)b0 * NPTS * 64, dist);
    k_topk<<<dim3(NPTS, nb_grp), 256, 0, stream>>>(dist, knn + (size_t)b0 * NPTS * KNN);
  }
  k_t0<64, 128><<<dim3(NBATCH * NPTS / 128, 2), 256, 0, stream>>>(x2, w3, t0buf);
  k_edge<64, 128, true><<<NBATCH * NPTS / 4, 256, 0, stream>>>(x2, knn, w3, t0buf,
                                                               g3, b3, x3);

  // ---- edge conv 4 (C=128 -> O=256)
  for (int b0 = 0; b0 < NBATCH; b0 += nb_grp) {
    k_dist<128><<<dim3(NPTS / 64, NPTS / 64, nb_grp), 256, 0, stream>>>(
        x3 + (size_t)b0 * NPTS * 128, dist);
    k_topk<<<dim3(NPTS, nb_grp), 256, 0, stream>>>(dist, knn + (size_t)b0 * NPTS * KNN);
  }
  k_t0<128, 256><<<dim3(NBATCH * NPTS / 128, 4), 256, 0, stream>>>(x3, w4, t0buf);
  k_edge<128, 256, true><<<NBATCH * NPTS / 4, 256, 0, stream>>>(x3, knn, w4, t0buf,
                                                                g4, b4, x4);

  // ---- point MLP (tiled GEMM) + pooling + head
  k_mlp5<<<dim3(NBATCH * NPTS / 128, 8), 256, 0, stream>>>(x1, x2, x3, x4, w5, g5, b5,
                                                           pmax, psum);
  k_pool<<<(NBATCH * 1024 + 255) / 256, 256, 0, stream>>>(pmax, psum, pooled);
  k_head<<<NBATCH, 256, 0, stream>>>(pooled, wl1, g6, b6, wl2, bl2, g7, b7, wl3, bl3,
                                     (float*)d_out);
}